// Round 11
// baseline (2468.108 us; speedup 1.0000x reference)
//
#include <hip/hip_runtime.h>
#include <hip/hip_bf16.h>
#include <math.h>

#define B 64
#define T 19
#define S 80
#define V 32000
#define E 256
#define U 1024
#define U3 (3*U)        // 3072
#define KXM (E+U)       // 1280

typedef unsigned short ushortT;
typedef __attribute__((ext_vector_type(8))) __bf16 bf16x8;
typedef __attribute__((ext_vector_type(4))) float f32x4;

__device__ __forceinline__ ushortT f2bf(float f) {
    unsigned int u = __float_as_uint(f);
    u = (u + 0x7FFF + ((u >> 16) & 1)) >> 16;   // RNE
    return (ushortT)u;
}
__device__ __forceinline__ float bf2f(ushortT u) {
    return __uint_as_float(((unsigned int)u) << 16);
}
__device__ __forceinline__ void split3(float v, ushortT& hi, ushortT& mid, ushortT& lo) {
    hi = f2bf(v);
    float r1 = v - bf2f(hi);
    mid = f2bf(r1);
    float r2 = r1 - bf2f(mid);
    lo = f2bf(r2);
}

// ---------------------------------------------------------------------------
// Pre-split weight pack: W fp32 [K][N] -> 3 bf16 planes in MFMA fragment order
// ---------------------------------------------------------------------------
__global__ __launch_bounds__(256) void pack_w3(
    const float* __restrict__ W, ushortT* __restrict__ Wp, int N, int K)
{
    int idx = blockIdx.x * 256 + threadIdx.x;
    int lane = idx & 63;
    int t = idx >> 6;
    int KC = K >> 5;
    int ntile = t / KC, kc = t - ntile * KC;
    int col = ntile * 16 + (lane & 15);
    int krow = kc * 32 + (lane >> 4) * 8;
    ushortT hi[8], mi[8], lo[8];
    #pragma unroll
    for (int i = 0; i < 8; i++)
        split3(W[(size_t)(krow + i) * N + col], hi[i], mi[i], lo[i]);
    size_t ps = (size_t)K * N;
    *(uint4*)(Wp + (size_t)idx * 8)          = *(uint4*)hi;
    *(uint4*)(Wp + ps + (size_t)idx * 8)     = *(uint4*)mi;
    *(uint4*)(Wp + 2 * ps + (size_t)idx * 8) = *(uint4*)lo;
}

// fc pack (single bf16, proven)
__global__ __launch_bounds__(256) void pack_w(
    const float* __restrict__ W, ushortT* __restrict__ Wp, int N, int K)
{
    int idx = blockIdx.x * 256 + threadIdx.x;
    int lane = idx & 63;
    int t = idx >> 6;
    int KC = K >> 5;
    int ntile = t / KC, kc = t - ntile * KC;
    int col = ntile * 16 + (lane & 15);
    int krow = kc * 32 + (lane >> 4) * 8;
    ushortT tmp[8];
    #pragma unroll
    for (int i = 0; i < 8; i++)
        tmp[i] = f2bf(W[(size_t)(krow + i) * N + col]);
    *(uint4*)(Wp + (size_t)idx * 8) = *(uint4*)tmp;
}

// ---------------------------------------------------------------------------
// Unified per-step split6 GEMM with K-split, 2-job fusion (blockIdx.z),
// optional 8-partial A-sum (nsum) and summed-A write-out (wout, x==0 blocks).
// ---------------------------------------------------------------------------
struct GemmJob {
    const float*   A;
    const float*   W;
    const ushortT* Wp;
    unsigned long long ps;
    int kc_base;
    int KCtot;
    float* Cpart;
    int lda;
    int nsum;        // 1 or 8 (sum partials spaced 64*lda apart)
    float* wout;     // if non-null: block x==0 writes summed A slice here
};

template<bool PRESPLIT>
__global__ __launch_bounds__(256) void gemm6_ks2(
    GemmJob j0, GemmJob j1, int N, int nkc)
{
    const int tid = threadIdx.x;
    const int lane = tid & 63;
    const int wave = tid >> 6;
    const GemmJob J = blockIdx.z ? j1 : j0;
    const int ks = blockIdx.y;
    const int ntile = blockIdx.x * 4 + wave;
    const int col = ntile * 16 + (lane & 15);
    const int kfrag = (lane >> 4) * 8;

    __shared__ __align__(16) ushortT Ahi[2048];
    __shared__ __align__(16) ushortT Amid[2048];
    __shared__ __align__(16) ushortT Alo[2048];

    f32x4 acc[4] = {};
    const int arow = (tid >> 6) * 16 + (tid & 15);
    const int kgof = ((tid >> 4) & 3) * 8;

    for (int c = 0; c < nkc; c++) {
        const int kc = ks * nkc + c;
        const float* ar = J.A + (size_t)arow * J.lda + kc * 32 + kgof;
        float av[8];
        *(float4*)(av)     = *(const float4*)(ar);
        *(float4*)(av + 4) = *(const float4*)(ar + 4);
        if (J.nsum == 8) {
            #pragma unroll
            for (int p = 1; p < 8; p++) {
                const float* ap = ar + (size_t)p * 64 * J.lda;
                float4 g0 = *(const float4*)(ap);
                float4 g1 = *(const float4*)(ap + 4);
                av[0] += g0.x; av[1] += g0.y; av[2] += g0.z; av[3] += g0.w;
                av[4] += g1.x; av[5] += g1.y; av[6] += g1.z; av[7] += g1.w;
            }
        }
        if (J.wout && blockIdx.x == 0) {
            float* w = J.wout + (size_t)arow * J.lda + kc * 32 + kgof;
            *(float4*)(w)     = *(const float4*)(av);
            *(float4*)(w + 4) = *(const float4*)(av + 4);
        }
        ushortT thi[8], tmi[8], tlo[8];
        #pragma unroll
        for (int i = 0; i < 8; i++) split3(av[i], thi[i], tmi[i], tlo[i]);
        ((uint4*)Ahi)[tid]  = *(const uint4*)thi;
        ((uint4*)Amid)[tid] = *(const uint4*)tmi;
        ((uint4*)Alo)[tid]  = *(const uint4*)tlo;

        bf16x8 bh, bm, bl;
        if constexpr (PRESPLIT) {
            size_t fi = (((size_t)ntile * J.KCtot + (J.kc_base + kc)) * 64 + lane) * 8;
            bh = *(const bf16x8*)(J.Wp + fi);
            bm = *(const bf16x8*)(J.Wp + J.ps + fi);
            bl = *(const bf16x8*)(J.Wp + 2 * J.ps + fi);
        } else {
            const float* wp = J.W + (size_t)((J.kc_base + kc) * 32 + kfrag) * N + col;
            ushortT whi[8], wmi[8], wlo[8];
            #pragma unroll
            for (int i = 0; i < 8; i++)
                split3(wp[(size_t)i * N], whi[i], wmi[i], wlo[i]);
            bh = *(const bf16x8*)whi;
            bm = *(const bf16x8*)wmi;
            bl = *(const bf16x8*)wlo;
        }

        __syncthreads();
        #pragma unroll
        for (int mi = 0; mi < 4; mi++) {
            bf16x8 ah = *(const bf16x8*)(Ahi  + (mi * 64 + lane) * 8);
            bf16x8 am = *(const bf16x8*)(Amid + (mi * 64 + lane) * 8);
            bf16x8 al = *(const bf16x8*)(Alo  + (mi * 64 + lane) * 8);
            acc[mi] = __builtin_amdgcn_mfma_f32_16x16x32_bf16(ah, bh, acc[mi], 0, 0, 0);
            acc[mi] = __builtin_amdgcn_mfma_f32_16x16x32_bf16(am, bh, acc[mi], 0, 0, 0);
            acc[mi] = __builtin_amdgcn_mfma_f32_16x16x32_bf16(ah, bm, acc[mi], 0, 0, 0);
            acc[mi] = __builtin_amdgcn_mfma_f32_16x16x32_bf16(am, bm, acc[mi], 0, 0, 0);
            acc[mi] = __builtin_amdgcn_mfma_f32_16x16x32_bf16(al, bh, acc[mi], 0, 0, 0);
            acc[mi] = __builtin_amdgcn_mfma_f32_16x16x32_bf16(ah, bl, acc[mi], 0, 0, 0);
        }
        __syncthreads();
    }

    float* cp = J.Cpart + (size_t)ks * 64 * N;
    #pragma unroll
    for (int mi = 0; mi < 4; mi++) {
        #pragma unroll
        for (int r = 0; r < 4; r++) {
            int m = mi * 16 + (lane >> 4) * 4 + r;
            cp[(size_t)m * N + col] = acc[mi][r];
        }
    }
}

// ---------------------------------------------------------------------------
// keys = memory @ mem_W: 2 n-tiles per wave, grid (U/128, B*S/64).
// ---------------------------------------------------------------------------
template<bool PRESPLIT>
__global__ __launch_bounds__(256) void gemm_keys(
    const float* __restrict__ A, const float* __restrict__ W,
    const ushortT* __restrict__ Wp, float* __restrict__ C)
{
    const int tid = threadIdx.x;
    const int lane = tid & 63;
    const int wave = tid >> 6;
    const int row0 = blockIdx.y * 64;
    const int nt0 = blockIdx.x * 8 + wave * 2;
    const int col0 = nt0 * 16 + (lane & 15);
    const int kfrag = (lane >> 4) * 8;

    __shared__ __align__(16) ushortT Ahi[2048];
    __shared__ __align__(16) ushortT Amid[2048];
    __shared__ __align__(16) ushortT Alo[2048];

    f32x4 acc[2][4] = {};
    const int arow = row0 + (tid >> 6) * 16 + (tid & 15);
    const int kgof = ((tid >> 4) & 3) * 8;
    const size_t ps = (size_t)U * U;

    for (int kc = 0; kc < 32; kc++) {
        const float* ar = A + (size_t)arow * U + kc * 32 + kgof;
        float av[8];
        *(float4*)(av)     = *(const float4*)(ar);
        *(float4*)(av + 4) = *(const float4*)(ar + 4);
        ushortT thi[8], tmi[8], tlo[8];
        #pragma unroll
        for (int i = 0; i < 8; i++) split3(av[i], thi[i], tmi[i], tlo[i]);
        ((uint4*)Ahi)[tid]  = *(const uint4*)thi;
        ((uint4*)Amid)[tid] = *(const uint4*)tmi;
        ((uint4*)Alo)[tid]  = *(const uint4*)tlo;

        bf16x8 bh[2], bm[2], bl[2];
        #pragma unroll
        for (int j = 0; j < 2; j++) {
            if constexpr (PRESPLIT) {
                size_t fi = (((size_t)(nt0 + j) * 32 + kc) * 64 + lane) * 8;
                bh[j] = *(const bf16x8*)(Wp + fi);
                bm[j] = *(const bf16x8*)(Wp + ps + fi);
                bl[j] = *(const bf16x8*)(Wp + 2 * ps + fi);
            } else {
                const float* wp = W + (size_t)(kc * 32 + kfrag) * U + col0 + j * 16;
                ushortT whi[8], wmi[8], wlo[8];
                #pragma unroll
                for (int i = 0; i < 8; i++)
                    split3(wp[(size_t)i * U], whi[i], wmi[i], wlo[i]);
                bh[j] = *(const bf16x8*)whi;
                bm[j] = *(const bf16x8*)wmi;
                bl[j] = *(const bf16x8*)wlo;
            }
        }

        __syncthreads();
        #pragma unroll
        for (int mi = 0; mi < 4; mi++) {
            bf16x8 ah = *(const bf16x8*)(Ahi  + (mi * 64 + lane) * 8);
            bf16x8 am = *(const bf16x8*)(Amid + (mi * 64 + lane) * 8);
            bf16x8 al = *(const bf16x8*)(Alo  + (mi * 64 + lane) * 8);
            #pragma unroll
            for (int j = 0; j < 2; j++) {
                acc[j][mi] = __builtin_amdgcn_mfma_f32_16x16x32_bf16(ah, bh[j], acc[j][mi], 0, 0, 0);
                acc[j][mi] = __builtin_amdgcn_mfma_f32_16x16x32_bf16(am, bh[j], acc[j][mi], 0, 0, 0);
                acc[j][mi] = __builtin_amdgcn_mfma_f32_16x16x32_bf16(ah, bm[j], acc[j][mi], 0, 0, 0);
                acc[j][mi] = __builtin_amdgcn_mfma_f32_16x16x32_bf16(am, bm[j], acc[j][mi], 0, 0, 0);
                acc[j][mi] = __builtin_amdgcn_mfma_f32_16x16x32_bf16(al, bh[j], acc[j][mi], 0, 0, 0);
                acc[j][mi] = __builtin_amdgcn_mfma_f32_16x16x32_bf16(ah, bl[j], acc[j][mi], 0, 0, 0);
            }
        }
        __syncthreads();
    }

    #pragma unroll
    for (int mi = 0; mi < 4; mi++) {
        #pragma unroll
        for (int r = 0; r < 4; r++) {
            int m = row0 + mi * 16 + (lane >> 4) * 4 + r;
            #pragma unroll
            for (int j = 0; j < 2; j++)
                C[(size_t)m * U + col0 + j * 16] = acc[j][mi][r];
        }
    }
}

// ---------------------------------------------------------------------------
// xe[t] = emb[x[:,t]] @ gk[0:256,:]   grid (U3/64, T)
// ---------------------------------------------------------------------------
template<bool PRESPLIT>
__global__ __launch_bounds__(256) void gemm_xe(
    const int* __restrict__ x, const float* __restrict__ emb,
    const float* __restrict__ gk, const ushortT* __restrict__ gkp,
    float* __restrict__ xe)
{
    const int tid = threadIdx.x;
    const int lane = tid & 63;
    const int wave = tid >> 6;
    const int t = blockIdx.y;
    const int ntile = blockIdx.x * 4 + wave;
    const int col = ntile * 16 + (lane & 15);
    const int kfrag = (lane >> 4) * 8;

    __shared__ __align__(16) ushortT Ahi[2048];
    __shared__ __align__(16) ushortT Amid[2048];
    __shared__ __align__(16) ushortT Alo[2048];

    f32x4 acc[4] = {};
    const int b = (tid >> 6) * 16 + (tid & 15);
    const int tok = x[b * T + t];
    const int kgof = ((tid >> 4) & 3) * 8;
    const size_t ps = (size_t)KXM * U3;

    for (int kc = 0; kc < E / 32; kc++) {
        const float* ar = emb + (size_t)tok * E + kc * 32 + kgof;
        float av[8];
        *(float4*)(av)     = *(const float4*)(ar);
        *(float4*)(av + 4) = *(const float4*)(ar + 4);
        ushortT thi[8], tmi[8], tlo[8];
        #pragma unroll
        for (int i = 0; i < 8; i++) split3(av[i], thi[i], tmi[i], tlo[i]);
        ((uint4*)Ahi)[tid]  = *(const uint4*)thi;
        ((uint4*)Amid)[tid] = *(const uint4*)tmi;
        ((uint4*)Alo)[tid]  = *(const uint4*)tlo;

        bf16x8 bh, bm, bl;
        if constexpr (PRESPLIT) {
            size_t fi = (((size_t)ntile * 40 + kc) * 64 + lane) * 8;   // gk KCtot=40
            bh = *(const bf16x8*)(gkp + fi);
            bm = *(const bf16x8*)(gkp + ps + fi);
            bl = *(const bf16x8*)(gkp + 2 * ps + fi);
        } else {
            const float* wp = gk + (size_t)(kc * 32 + kfrag) * U3 + col;
            ushortT whi[8], wmi[8], wlo[8];
            #pragma unroll
            for (int i = 0; i < 8; i++)
                split3(wp[(size_t)i * U3], whi[i], wmi[i], wlo[i]);
            bh = *(const bf16x8*)whi;
            bm = *(const bf16x8*)wmi;
            bl = *(const bf16x8*)wlo;
        }

        __syncthreads();
        #pragma unroll
        for (int mi = 0; mi < 4; mi++) {
            bf16x8 ah = *(const bf16x8*)(Ahi  + (mi * 64 + lane) * 8);
            bf16x8 am = *(const bf16x8*)(Amid + (mi * 64 + lane) * 8);
            bf16x8 al = *(const bf16x8*)(Alo  + (mi * 64 + lane) * 8);
            acc[mi] = __builtin_amdgcn_mfma_f32_16x16x32_bf16(ah, bh, acc[mi], 0, 0, 0);
            acc[mi] = __builtin_amdgcn_mfma_f32_16x16x32_bf16(am, bh, acc[mi], 0, 0, 0);
            acc[mi] = __builtin_amdgcn_mfma_f32_16x16x32_bf16(ah, bm, acc[mi], 0, 0, 0);
            acc[mi] = __builtin_amdgcn_mfma_f32_16x16x32_bf16(am, bm, acc[mi], 0, 0, 0);
            acc[mi] = __builtin_amdgcn_mfma_f32_16x16x32_bf16(al, bh, acc[mi], 0, 0, 0);
            acc[mi] = __builtin_amdgcn_mfma_f32_16x16x32_bf16(ah, bl, acc[mi], 0, 0, 0);
        }
        __syncthreads();
    }

    #pragma unroll
    for (int mi = 0; mi < 4; mi++) {
        #pragma unroll
        for (int r = 0; r < 4; r++) {
            int m = mi * 16 + (lane >> 4) * 4 + r;
            xe[((size_t)t * 64 + m) * U3 + col] = acc[mi][r];
        }
    }
}

// ---------------------------------------------------------------------------
// Batched fc GEMM v3: M-tile 256 (4 t-groups per block), weights in registers
// across the 4 t's. XCD-pinned: bid = (g*5+mt)*8 + x, strip = g*8 + x.
// Per-t MFMA accumulation order identical to R10 -> bit-identical logits.
// ---------------------------------------------------------------------------
__global__ __launch_bounds__(256) void gemm_fcB(
    const float* __restrict__ A, const ushortT* __restrict__ Wp,
    const float* __restrict__ bias, float* __restrict__ C)
{
    const int xcd = blockIdx.x & 7;
    const int rem = blockIdx.x >> 3;        // g*5 + mt
    const int g = rem / 5;
    const int mt = rem - g * 5;
    const int strip = g * 8 + xcd;
    if (strip >= V / 128) return;
    const int ntt = min(4, T - mt * 4);     // 4,4,4,4,3

    const int tid = threadIdx.x;
    const int lane = tid & 63;
    const int wave = tid >> 6;
    const int nt0 = strip * 8 + wave * 2;
    const int col0 = nt0 * 16 + (lane & 15);

    __shared__ __align__(16) ushortT As[4][2][2048];

    f32x4 acc[4][2][4] = {};                // [tt][j][mi]
    const int arow = (tid >> 6) * 16 + (tid & 15);
    const int kgof = ((tid >> 4) & 3) * 8;

    for (int it = 0; it < 16; it++) {
        #pragma unroll
        for (int tt = 0; tt < 4; tt++) {
            if (tt < ntt) {
                #pragma unroll
                for (int c = 0; c < 2; c++) {
                    const float* ar = A + ((size_t)(mt * 4 + tt) * 64 + arow) * U
                                        + (it * 2 + c) * 32 + kgof;
                    float4 f0 = *(const float4*)(ar);
                    float4 f1 = *(const float4*)(ar + 4);
                    ushortT tmp[8] = { f2bf(f0.x), f2bf(f0.y), f2bf(f0.z), f2bf(f0.w),
                                       f2bf(f1.x), f2bf(f1.y), f2bf(f1.z), f2bf(f1.w) };
                    ((uint4*)As[tt][c])[tid] = *(const uint4*)tmp;
                }
            }
        }
        bf16x8 b[2][2];
        #pragma unroll
        for (int c = 0; c < 2; c++)
            #pragma unroll
            for (int j = 0; j < 2; j++)
                b[c][j] = *(const bf16x8*)(Wp +
                    (((size_t)(nt0 + j) * 32 + it * 2 + c) * 64 + lane) * 8);
        __syncthreads();
        #pragma unroll
        for (int tt = 0; tt < 4; tt++) {
            if (tt < ntt) {
                #pragma unroll
                for (int c = 0; c < 2; c++) {
                    #pragma unroll
                    for (int mi = 0; mi < 4; mi++) {
                        bf16x8 a = *(const bf16x8*)(&As[tt][c][(mi * 64 + lane) * 8]);
                        #pragma unroll
                        for (int j = 0; j < 2; j++)
                            acc[tt][j][mi] = __builtin_amdgcn_mfma_f32_16x16x32_bf16(
                                a, b[c][j], acc[tt][j][mi], 0, 0, 0);
                    }
                }
            }
        }
        __syncthreads();
    }

    for (int tt = 0; tt < ntt; tt++) {
        float* Ct = C + (size_t)(mt * 4 + tt) * V;
        #pragma unroll
        for (int j = 0; j < 2; j++) {
            const float bv = bias[col0 + j * 16];
            #pragma unroll
            for (int mi = 0; mi < 4; mi++) {
                #pragma unroll
                for (int r = 0; r < 4; r++) {
                    int m = mi * 16 + (lane >> 4) * 4 + r;
                    __builtin_nontemporal_store(acc[tt][j][mi][r] + bv,
                        &Ct[(size_t)m * (T * V) + col0 + j * 16]);
                }
            }
        }
    }
}

// ---------------------------------------------------------------------------
// Fused GRU gates + scores (R8-proven): one block per batch b.
// ---------------------------------------------------------------------------
__global__ __launch_bounds__(256) void gs_fused(
    const float* __restrict__ xe_t, const float* __restrict__ xm_part,
    const float* __restrict__ hm_part, const float* __restrict__ gb,
    const float* __restrict__ keys, float* __restrict__ h,
    float* __restrict__ cat2, float* __restrict__ scores, int use_xm)
{
    const int b = blockIdx.x;
    const int tid = threadIdx.x;
    __shared__ __align__(16) float hs[U];

    #pragma unroll
    for (int k = 0; k < 4; k++) {
        int u = k * 256 + tid;
        float xv[3], hv[3];
        #pragma unroll
        for (int g = 0; g < 3; g++) {
            int j = g * U + u;
            float xs = xe_t[(size_t)b * U3 + j] + gb[j];
            float hsum = gb[U3 + j];
            if (use_xm) {
                #pragma unroll
                for (int p = 0; p < 4; p++)
                    xs += xm_part[((size_t)p * 64 + b) * U3 + j];
            }
            #pragma unroll
            for (int p = 0; p < 4; p++)
                hsum += hm_part[((size_t)p * 64 + b) * U3 + j];
            xv[g] = xs; hv[g] = hsum;
        }
        float z = 1.f / (1.f + expf(-(xv[0] + hv[0])));
        float r = 1.f / (1.f + expf(-(xv[1] + hv[1])));
        float hh = tanhf(xv[2] + r * hv[2]);
        float hn = z * h[(size_t)b * U + u] + (1.f - z) * hh;
        h[(size_t)b * U + u] = hn;
        hs[u] = hn;
        cat2[(size_t)b * 2 * U + u] = hn;
    }
    __syncthreads();

    const int wave = tid >> 6, lane = tid & 63;
    for (int s = wave; s < S; s += 4) {
        const float* kr = keys + ((size_t)b * S + s) * U;
        float acc = 0.f;
        #pragma unroll
        for (int c = 0; c < 4; c++) {
            int off = c * 256 + lane * 4;
            float4 kv = *(const float4*)(kr + off);
            float4 hv4 = *(const float4*)(hs + off);
            acc += kv.x * hv4.x + kv.y * hv4.y + kv.z * hv4.z + kv.w * hv4.w;
        }
        #pragma unroll
        for (int off = 32; off > 0; off >>= 1) acc += __shfl_down(acc, off);
        if (lane == 0) scores[b * S + s] = acc;
    }
}

// softmax + context (cat2 second half); grid (B, U/256) — R8-proven
__global__ __launch_bounds__(256) void ctxcat2_kernel(
    const float* __restrict__ scores, const float* __restrict__ memory,
    float* __restrict__ cat2)
{
    const int b = blockIdx.x;
    const int u = blockIdx.y * 256 + threadIdx.x;
    __shared__ float p[S];
    __shared__ float pn[S];
    if (threadIdx.x < S) p[threadIdx.x] = scores[b * S + threadIdx.x];
    __syncthreads();
    float m = -1e30f;
    #pragma unroll 8
    for (int s = 0; s < S; s++) m = fmaxf(m, p[s]);
    float sum = 0.f;
    #pragma unroll 8
    for (int s = 0; s < S; s++) sum += expf(p[s] - m);
    if (threadIdx.x < S) pn[threadIdx.x] = expf(p[threadIdx.x] - m) / sum;
    __syncthreads();
    float acc = 0.f;
    #pragma unroll 8
    for (int s = 0; s < S; s++)
        acc += pn[s] * memory[((size_t)b * S + s) * U + u];
    cat2[(size_t)b * 2 * U + U + u] = acc;
}

// attnv = sum8(attn_part) — used only once, for t = T-1
__global__ __launch_bounds__(256) void reduce_attnv(
    const float* __restrict__ attn_part, float* __restrict__ dst)
{
    int idx = blockIdx.x * 256 + threadIdx.x;   // B*U
    float s = 0.f;
    #pragma unroll
    for (int p = 0; p < 8; p++) s += attn_part[(size_t)p * B * U + idx];
    dst[idx] = s;
}

// ---------------------------------------------------------------------------
extern "C" void kernel_launch(void* const* d_in, const int* in_sizes, int n_in,
                              void* d_out, int out_size, void* d_ws, size_t ws_size,
                              hipStream_t stream)
{
    const int*   x      = (const int*)  d_in[0];
    const float* enc    = (const float*)d_in[1];
    const float* memory = (const float*)d_in[2];
    const float* emb    = (const float*)d_in[3];
    const float* gk     = (const float*)d_in[4];
    const float* grk    = (const float*)d_in[5];
    const float* gb     = (const float*)d_in[6];
    const float* memW   = (const float*)d_in[7];
    const float* attnW  = (const float*)d_in[8];
    const float* fcW    = (const float*)d_in[9];
    const float* fcb    = (const float*)d_in[10];
    float* out = (float*)d_out;

    char* p = (char*)d_ws;
    auto alloc = [&](size_t bytes) { char* r = p; p += (bytes + 255) & ~(size_t)255; return r; };
    ushortT* fcWp      = (ushortT*)alloc((size_t)U * V * 2);
    float*   keys      = (float*)  alloc((size_t)B * S * U * 4);
    float*   xe        = (float*)  alloc((size_t)T * B * U3 * 4);
    float*   xm_part   = (float*)  alloc((size_t)4 * B * U3 * 4);
    float*   hm_part   = (float*)  alloc((size_t)4 * B * U3 * 4);
    float*   attn_part = (float*)  alloc((size_t)8 * B * U * 4);
    float*   h         = (float*)  alloc((size_t)B * U * 4);
    float*   attnv_all = (float*)  alloc((size_t)T * B * U * 4);
    float*   cat2      = (float*)  alloc((size_t)B * 2 * U * 4);
    float*   scores    = (float*)  alloc((size_t)B * S * 4);
    ushortT* gkp       = (ushortT*)alloc((size_t)KXM * U3 * 2 * 3);
    ushortT* grkp      = (ushortT*)alloc((size_t)U * U3 * 2 * 3);
    ushortT* awp       = (ushortT*)alloc((size_t)2 * U * U * 2 * 3);
    ushortT* mwp       = (ushortT*)alloc((size_t)U * U * 2 * 3);
    const bool PS = (size_t)(p - (char*)d_ws) <= ws_size;

    dim3 blk(256);

    if (PS) {
        pack_w3<<<(size_t)KXM * U3 / 8 / 256, blk, 0, stream>>>(gk, gkp, U3, KXM);
        pack_w3<<<(size_t)U * U3 / 8 / 256, blk, 0, stream>>>(grk, grkp, U3, U);
        pack_w3<<<(size_t)2 * U * U / 8 / 256, blk, 0, stream>>>(attnW, awp, U, 2 * U);
        pack_w3<<<(size_t)U * U / 8 / 256, blk, 0, stream>>>(memW, mwp, U, U);
    }
    pack_w<<<(size_t)U * V / 8 / 256, blk, 0, stream>>>(fcW, fcWp, V, U);
    (void)hipMemcpyAsync(h, enc, (size_t)B * U * sizeof(float),
                         hipMemcpyDeviceToDevice, stream);

    if (PS) gemm_xe<true><<<dim3(U3 / 64, T), blk, 0, stream>>>(x, emb, gk, gkp, xe);
    else    gemm_xe<false><<<dim3(U3 / 64, T), blk, 0, stream>>>(x, emb, gk, gkp, xe);

    if (PS) gemm_keys<true><<<dim3(U / 128, B * S / 64), blk, 0, stream>>>(memory, memW, mwp, keys);
    else    gemm_keys<false><<<dim3(U / 128, B * S / 64), blk, 0, stream>>>(memory, memW, mwp, keys);

    GemmJob job_hm = { h,    grk,   grkp, (size_t)U * U3,    0, 32, hm_part,   U,
                       1, nullptr };
    GemmJob job_at = { cat2, attnW, awp,  (size_t)2 * U * U, 0, 64, attn_part, 2 * U,
                       1, nullptr };

    for (int t = 0; t < T; t++) {
        // xm job reads attn_part (8 partials summed in-staging, same p-order
        // as reduce_attnv) and block x==0 writes summed attnv to attnv_all[t-1].
        GemmJob job_xm = { attn_part, gk, gkp, (size_t)KXM * U3, 8, 40, xm_part, U,
                           8, (t > 0) ? (attnv_all + (size_t)(t - 1) * B * U) : nullptr };
        dim3 g1(U3 / 64, 4, t > 0 ? 2 : 1);
        if (PS) gemm6_ks2<true><<<g1, blk, 0, stream>>>(job_hm, job_xm, U3, 8);
        else    gemm6_ks2<false><<<g1, blk, 0, stream>>>(job_hm, job_xm, U3, 8);
        gs_fused<<<B, blk, 0, stream>>>(
            xe + (size_t)t * B * U3, xm_part, hm_part, gb, keys, h, cat2,
            scores, t > 0 ? 1 : 0);
        ctxcat2_kernel<<<dim3(B, U / 256), blk, 0, stream>>>(scores, memory, cat2);
        dim3 g2(U / 64, 8, 1);
        if (PS) gemm6_ks2<true><<<g2, blk, 0, stream>>>(job_at, job_at, U, 8);
        else    gemm6_ks2<false><<<g2, blk, 0, stream>>>(job_at, job_at, U, 8);
    }

    // last step's attnv (no following g1 to fold it into)
    reduce_attnv<<<B * U / 256, blk, 0, stream>>>(
        attn_part, attnv_all + (size_t)(T - 1) * B * U);

    // all logits at once: [T*64, U] @ [U, V] + fcb (M-tile 256, XCD-pinned)
    gemm_fcB<<<32 * 5 * 8, blk, 0, stream>>>(attnv_all, fcWp, fcb, out);
}

// Round 12
// 1566.068 us; speedup vs baseline: 1.5760x; 1.5760x over previous
//
#include <hip/hip_runtime.h>
#include <hip/hip_bf16.h>
#include <math.h>

#define B 64
#define T 19
#define S 80
#define V 32000
#define E 256
#define U 1024
#define U3 (3*U)        // 3072
#define KXM (E+U)       // 1280

typedef unsigned short ushortT;
typedef __attribute__((ext_vector_type(8))) __bf16 bf16x8;
typedef __attribute__((ext_vector_type(4))) float f32x4;

__device__ __forceinline__ ushortT f2bf(float f) {
    unsigned int u = __float_as_uint(f);
    u = (u + 0x7FFF + ((u >> 16) & 1)) >> 16;   // RNE
    return (ushortT)u;
}
__device__ __forceinline__ float bf2f(ushortT u) {
    return __uint_as_float(((unsigned int)u) << 16);
}
__device__ __forceinline__ void split3(float v, ushortT& hi, ushortT& mid, ushortT& lo) {
    hi = f2bf(v);
    float r1 = v - bf2f(hi);
    mid = f2bf(r1);
    float r2 = r1 - bf2f(mid);
    lo = f2bf(r2);
}

// ---------------------------------------------------------------------------
// Pre-split weight pack: W fp32 [K][N] -> 3 bf16 planes in MFMA fragment order
// ---------------------------------------------------------------------------
__global__ __launch_bounds__(256) void pack_w3(
    const float* __restrict__ W, ushortT* __restrict__ Wp, int N, int K)
{
    int idx = blockIdx.x * 256 + threadIdx.x;
    int lane = idx & 63;
    int t = idx >> 6;
    int KC = K >> 5;
    int ntile = t / KC, kc = t - ntile * KC;
    int col = ntile * 16 + (lane & 15);
    int krow = kc * 32 + (lane >> 4) * 8;
    ushortT hi[8], mi[8], lo[8];
    #pragma unroll
    for (int i = 0; i < 8; i++)
        split3(W[(size_t)(krow + i) * N + col], hi[i], mi[i], lo[i]);
    size_t ps = (size_t)K * N;
    *(uint4*)(Wp + (size_t)idx * 8)          = *(uint4*)hi;
    *(uint4*)(Wp + ps + (size_t)idx * 8)     = *(uint4*)mi;
    *(uint4*)(Wp + 2 * ps + (size_t)idx * 8) = *(uint4*)lo;
}

// fc pack (single bf16, proven)
__global__ __launch_bounds__(256) void pack_w(
    const float* __restrict__ W, ushortT* __restrict__ Wp, int N, int K)
{
    int idx = blockIdx.x * 256 + threadIdx.x;
    int lane = idx & 63;
    int t = idx >> 6;
    int KC = K >> 5;
    int ntile = t / KC, kc = t - ntile * KC;
    int col = ntile * 16 + (lane & 15);
    int krow = kc * 32 + (lane >> 4) * 8;
    ushortT tmp[8];
    #pragma unroll
    for (int i = 0; i < 8; i++)
        tmp[i] = f2bf(W[(size_t)(krow + i) * N + col]);
    *(uint4*)(Wp + (size_t)idx * 8) = *(uint4*)tmp;
}

// ---------------------------------------------------------------------------
// Unified per-step split6 GEMM with K-split and 2-job fusion (blockIdx.z).
// (R10-proven version, no staging-sum extras.)
// ---------------------------------------------------------------------------
struct GemmJob {
    const float*   A;
    const float*   W;
    const ushortT* Wp;
    unsigned long long ps;
    int kc_base;
    int KCtot;
    float* Cpart;
    int lda;
};

template<bool PRESPLIT>
__global__ __launch_bounds__(256) void gemm6_ks2(
    GemmJob j0, GemmJob j1, int N, int nkc)
{
    const int tid = threadIdx.x;
    const int lane = tid & 63;
    const int wave = tid >> 6;
    const GemmJob J = blockIdx.z ? j1 : j0;
    const int ks = blockIdx.y;
    const int ntile = blockIdx.x * 4 + wave;
    const int col = ntile * 16 + (lane & 15);
    const int kfrag = (lane >> 4) * 8;

    __shared__ __align__(16) ushortT Ahi[2048];
    __shared__ __align__(16) ushortT Amid[2048];
    __shared__ __align__(16) ushortT Alo[2048];

    f32x4 acc[4] = {};
    const int arow = (tid >> 6) * 16 + (tid & 15);
    const int kgof = ((tid >> 4) & 3) * 8;

    for (int c = 0; c < nkc; c++) {
        const int kc = ks * nkc + c;
        const float* ar = J.A + (size_t)arow * J.lda + kc * 32 + kgof;
        float av[8];
        *(float4*)(av)     = *(const float4*)(ar);
        *(float4*)(av + 4) = *(const float4*)(ar + 4);
        ushortT thi[8], tmi[8], tlo[8];
        #pragma unroll
        for (int i = 0; i < 8; i++) split3(av[i], thi[i], tmi[i], tlo[i]);
        ((uint4*)Ahi)[tid]  = *(const uint4*)thi;
        ((uint4*)Amid)[tid] = *(const uint4*)tmi;
        ((uint4*)Alo)[tid]  = *(const uint4*)tlo;

        bf16x8 bh, bm, bl;
        if constexpr (PRESPLIT) {
            size_t fi = (((size_t)ntile * J.KCtot + (J.kc_base + kc)) * 64 + lane) * 8;
            bh = *(const bf16x8*)(J.Wp + fi);
            bm = *(const bf16x8*)(J.Wp + J.ps + fi);
            bl = *(const bf16x8*)(J.Wp + 2 * J.ps + fi);
        } else {
            const float* wp = J.W + (size_t)((J.kc_base + kc) * 32 + kfrag) * N + col;
            ushortT whi[8], wmi[8], wlo[8];
            #pragma unroll
            for (int i = 0; i < 8; i++)
                split3(wp[(size_t)i * N], whi[i], wmi[i], wlo[i]);
            bh = *(const bf16x8*)whi;
            bm = *(const bf16x8*)wmi;
            bl = *(const bf16x8*)wlo;
        }

        __syncthreads();
        #pragma unroll
        for (int mi = 0; mi < 4; mi++) {
            bf16x8 ah = *(const bf16x8*)(Ahi  + (mi * 64 + lane) * 8);
            bf16x8 am = *(const bf16x8*)(Amid + (mi * 64 + lane) * 8);
            bf16x8 al = *(const bf16x8*)(Alo  + (mi * 64 + lane) * 8);
            acc[mi] = __builtin_amdgcn_mfma_f32_16x16x32_bf16(ah, bh, acc[mi], 0, 0, 0);
            acc[mi] = __builtin_amdgcn_mfma_f32_16x16x32_bf16(am, bh, acc[mi], 0, 0, 0);
            acc[mi] = __builtin_amdgcn_mfma_f32_16x16x32_bf16(ah, bm, acc[mi], 0, 0, 0);
            acc[mi] = __builtin_amdgcn_mfma_f32_16x16x32_bf16(am, bm, acc[mi], 0, 0, 0);
            acc[mi] = __builtin_amdgcn_mfma_f32_16x16x32_bf16(al, bh, acc[mi], 0, 0, 0);
            acc[mi] = __builtin_amdgcn_mfma_f32_16x16x32_bf16(ah, bl, acc[mi], 0, 0, 0);
        }
        __syncthreads();
    }

    float* cp = J.Cpart + (size_t)ks * 64 * N;
    #pragma unroll
    for (int mi = 0; mi < 4; mi++) {
        #pragma unroll
        for (int r = 0; r < 4; r++) {
            int m = mi * 16 + (lane >> 4) * 4 + r;
            cp[(size_t)m * N + col] = acc[mi][r];
        }
    }
}

// ---------------------------------------------------------------------------
// keys = memory @ mem_W: 2 n-tiles per wave, grid (U/128, B*S/64).
// ---------------------------------------------------------------------------
template<bool PRESPLIT>
__global__ __launch_bounds__(256) void gemm_keys(
    const float* __restrict__ A, const float* __restrict__ W,
    const ushortT* __restrict__ Wp, float* __restrict__ C)
{
    const int tid = threadIdx.x;
    const int lane = tid & 63;
    const int wave = tid >> 6;
    const int row0 = blockIdx.y * 64;
    const int nt0 = blockIdx.x * 8 + wave * 2;
    const int col0 = nt0 * 16 + (lane & 15);
    const int kfrag = (lane >> 4) * 8;

    __shared__ __align__(16) ushortT Ahi[2048];
    __shared__ __align__(16) ushortT Amid[2048];
    __shared__ __align__(16) ushortT Alo[2048];

    f32x4 acc[2][4] = {};
    const int arow = row0 + (tid >> 6) * 16 + (tid & 15);
    const int kgof = ((tid >> 4) & 3) * 8;
    const size_t ps = (size_t)U * U;

    for (int kc = 0; kc < 32; kc++) {
        const float* ar = A + (size_t)arow * U + kc * 32 + kgof;
        float av[8];
        *(float4*)(av)     = *(const float4*)(ar);
        *(float4*)(av + 4) = *(const float4*)(ar + 4);
        ushortT thi[8], tmi[8], tlo[8];
        #pragma unroll
        for (int i = 0; i < 8; i++) split3(av[i], thi[i], tmi[i], tlo[i]);
        ((uint4*)Ahi)[tid]  = *(const uint4*)thi;
        ((uint4*)Amid)[tid] = *(const uint4*)tmi;
        ((uint4*)Alo)[tid]  = *(const uint4*)tlo;

        bf16x8 bh[2], bm[2], bl[2];
        #pragma unroll
        for (int j = 0; j < 2; j++) {
            if constexpr (PRESPLIT) {
                size_t fi = (((size_t)(nt0 + j) * 32 + kc) * 64 + lane) * 8;
                bh[j] = *(const bf16x8*)(Wp + fi);
                bm[j] = *(const bf16x8*)(Wp + ps + fi);
                bl[j] = *(const bf16x8*)(Wp + 2 * ps + fi);
            } else {
                const float* wp = W + (size_t)(kc * 32 + kfrag) * U + col0 + j * 16;
                ushortT whi[8], wmi[8], wlo[8];
                #pragma unroll
                for (int i = 0; i < 8; i++)
                    split3(wp[(size_t)i * U], whi[i], wmi[i], wlo[i]);
                bh[j] = *(const bf16x8*)whi;
                bm[j] = *(const bf16x8*)wmi;
                bl[j] = *(const bf16x8*)wlo;
            }
        }

        __syncthreads();
        #pragma unroll
        for (int mi = 0; mi < 4; mi++) {
            bf16x8 ah = *(const bf16x8*)(Ahi  + (mi * 64 + lane) * 8);
            bf16x8 am = *(const bf16x8*)(Amid + (mi * 64 + lane) * 8);
            bf16x8 al = *(const bf16x8*)(Alo  + (mi * 64 + lane) * 8);
            #pragma unroll
            for (int j = 0; j < 2; j++) {
                acc[j][mi] = __builtin_amdgcn_mfma_f32_16x16x32_bf16(ah, bh[j], acc[j][mi], 0, 0, 0);
                acc[j][mi] = __builtin_amdgcn_mfma_f32_16x16x32_bf16(am, bh[j], acc[j][mi], 0, 0, 0);
                acc[j][mi] = __builtin_amdgcn_mfma_f32_16x16x32_bf16(ah, bm[j], acc[j][mi], 0, 0, 0);
                acc[j][mi] = __builtin_amdgcn_mfma_f32_16x16x32_bf16(am, bm[j], acc[j][mi], 0, 0, 0);
                acc[j][mi] = __builtin_amdgcn_mfma_f32_16x16x32_bf16(al, bh[j], acc[j][mi], 0, 0, 0);
                acc[j][mi] = __builtin_amdgcn_mfma_f32_16x16x32_bf16(ah, bl[j], acc[j][mi], 0, 0, 0);
            }
        }
        __syncthreads();
    }

    #pragma unroll
    for (int mi = 0; mi < 4; mi++) {
        #pragma unroll
        for (int r = 0; r < 4; r++) {
            int m = row0 + mi * 16 + (lane >> 4) * 4 + r;
            #pragma unroll
            for (int j = 0; j < 2; j++)
                C[(size_t)m * U + col0 + j * 16] = acc[j][mi][r];
        }
    }
}

// ---------------------------------------------------------------------------
// xe[t] = emb[x[:,t]] @ gk[0:256,:]   grid (U3/64, T)
// ---------------------------------------------------------------------------
template<bool PRESPLIT>
__global__ __launch_bounds__(256) void gemm_xe(
    const int* __restrict__ x, const float* __restrict__ emb,
    const float* __restrict__ gk, const ushortT* __restrict__ gkp,
    float* __restrict__ xe)
{
    const int tid = threadIdx.x;
    const int lane = tid & 63;
    const int wave = tid >> 6;
    const int t = blockIdx.y;
    const int ntile = blockIdx.x * 4 + wave;
    const int col = ntile * 16 + (lane & 15);
    const int kfrag = (lane >> 4) * 8;

    __shared__ __align__(16) ushortT Ahi[2048];
    __shared__ __align__(16) ushortT Amid[2048];
    __shared__ __align__(16) ushortT Alo[2048];

    f32x4 acc[4] = {};
    const int b = (tid >> 6) * 16 + (tid & 15);
    const int tok = x[b * T + t];
    const int kgof = ((tid >> 4) & 3) * 8;
    const size_t ps = (size_t)KXM * U3;

    for (int kc = 0; kc < E / 32; kc++) {
        const float* ar = emb + (size_t)tok * E + kc * 32 + kgof;
        float av[8];
        *(float4*)(av)     = *(const float4*)(ar);
        *(float4*)(av + 4) = *(const float4*)(ar + 4);
        ushortT thi[8], tmi[8], tlo[8];
        #pragma unroll
        for (int i = 0; i < 8; i++) split3(av[i], thi[i], tmi[i], tlo[i]);
        ((uint4*)Ahi)[tid]  = *(const uint4*)thi;
        ((uint4*)Amid)[tid] = *(const uint4*)tmi;
        ((uint4*)Alo)[tid]  = *(const uint4*)tlo;

        bf16x8 bh, bm, bl;
        if constexpr (PRESPLIT) {
            size_t fi = (((size_t)ntile * 40 + kc) * 64 + lane) * 8;   // gk KCtot=40
            bh = *(const bf16x8*)(gkp + fi);
            bm = *(const bf16x8*)(gkp + ps + fi);
            bl = *(const bf16x8*)(gkp + 2 * ps + fi);
        } else {
            const float* wp = gk + (size_t)(kc * 32 + kfrag) * U3 + col;
            ushortT whi[8], wmi[8], wlo[8];
            #pragma unroll
            for (int i = 0; i < 8; i++)
                split3(wp[(size_t)i * U3], whi[i], wmi[i], wlo[i]);
            bh = *(const bf16x8*)whi;
            bm = *(const bf16x8*)wmi;
            bl = *(const bf16x8*)wlo;
        }

        __syncthreads();
        #pragma unroll
        for (int mi = 0; mi < 4; mi++) {
            bf16x8 ah = *(const bf16x8*)(Ahi  + (mi * 64 + lane) * 8);
            bf16x8 am = *(const bf16x8*)(Amid + (mi * 64 + lane) * 8);
            bf16x8 al = *(const bf16x8*)(Alo  + (mi * 64 + lane) * 8);
            acc[mi] = __builtin_amdgcn_mfma_f32_16x16x32_bf16(ah, bh, acc[mi], 0, 0, 0);
            acc[mi] = __builtin_amdgcn_mfma_f32_16x16x32_bf16(am, bh, acc[mi], 0, 0, 0);
            acc[mi] = __builtin_amdgcn_mfma_f32_16x16x32_bf16(ah, bm, acc[mi], 0, 0, 0);
            acc[mi] = __builtin_amdgcn_mfma_f32_16x16x32_bf16(am, bm, acc[mi], 0, 0, 0);
            acc[mi] = __builtin_amdgcn_mfma_f32_16x16x32_bf16(al, bh, acc[mi], 0, 0, 0);
            acc[mi] = __builtin_amdgcn_mfma_f32_16x16x32_bf16(ah, bl, acc[mi], 0, 0, 0);
        }
        __syncthreads();
    }

    #pragma unroll
    for (int mi = 0; mi < 4; mi++) {
        #pragma unroll
        for (int r = 0; r < 4; r++) {
            int m = mi * 16 + (lane >> 4) * 4 + r;
            xe[((size_t)t * 64 + m) * U3 + col] = acc[mi][r];
        }
    }
}

// ---------------------------------------------------------------------------
// Batched fc GEMM v4: M-tile 256 (4 t-groups/block), weights in registers
// across the 4 t's. XCD-pinned: bid = (g*5+mt)*8 + x, strip = g*8 + x.
// SPILL FIX vs R11: epilogue fully unrolled with compile-time acc indices
// (runtime `for tt<ntt` forced acc into scratch -> 4.5 GB/dispatch traffic).
// ---------------------------------------------------------------------------
__global__ __launch_bounds__(256) void gemm_fcB(
    const float* __restrict__ A, const ushortT* __restrict__ Wp,
    const float* __restrict__ bias, float* __restrict__ C)
{
    const int xcd = blockIdx.x & 7;
    const int rem = blockIdx.x >> 3;        // g*5 + mt
    const int g = rem / 5;
    const int mt = rem - g * 5;
    const int strip = g * 8 + xcd;
    if (strip >= V / 128) return;
    const int ntt = (mt == 4) ? 3 : 4;      // T = 19 = 4*4 + 3

    const int tid = threadIdx.x;
    const int lane = tid & 63;
    const int wave = tid >> 6;
    const int nt0 = strip * 8 + wave * 2;
    const int col0 = nt0 * 16 + (lane & 15);

    __shared__ __align__(16) ushortT As[4][2][2048];

    f32x4 acc[4][2][4] = {};                // [tt][j][mi] — all static indexing
    const int arow = (tid >> 6) * 16 + (tid & 15);
    const int kgof = ((tid >> 4) & 3) * 8;

    for (int it = 0; it < 16; it++) {
        #pragma unroll
        for (int tt = 0; tt < 4; tt++) {
            if (tt < ntt) {
                #pragma unroll
                for (int c = 0; c < 2; c++) {
                    const float* ar = A + ((size_t)(mt * 4 + tt) * 64 + arow) * U
                                        + (it * 2 + c) * 32 + kgof;
                    float4 f0 = *(const float4*)(ar);
                    float4 f1 = *(const float4*)(ar + 4);
                    ushortT tmp[8] = { f2bf(f0.x), f2bf(f0.y), f2bf(f0.z), f2bf(f0.w),
                                       f2bf(f1.x), f2bf(f1.y), f2bf(f1.z), f2bf(f1.w) };
                    ((uint4*)As[tt][c])[tid] = *(const uint4*)tmp;
                }
            }
        }
        bf16x8 b[2][2];
        #pragma unroll
        for (int c = 0; c < 2; c++)
            #pragma unroll
            for (int j = 0; j < 2; j++)
                b[c][j] = *(const bf16x8*)(Wp +
                    (((size_t)(nt0 + j) * 32 + it * 2 + c) * 64 + lane) * 8);
        __syncthreads();
        #pragma unroll
        for (int tt = 0; tt < 4; tt++) {
            if (tt < ntt) {
                #pragma unroll
                for (int c = 0; c < 2; c++) {
                    #pragma unroll
                    for (int mi = 0; mi < 4; mi++) {
                        bf16x8 a = *(const bf16x8*)(&As[tt][c][(mi * 64 + lane) * 8]);
                        #pragma unroll
                        for (int j = 0; j < 2; j++)
                            acc[tt][j][mi] = __builtin_amdgcn_mfma_f32_16x16x32_bf16(
                                a, b[c][j], acc[tt][j][mi], 0, 0, 0);
                    }
                }
            }
        }
        __syncthreads();
    }

    #pragma unroll
    for (int tt = 0; tt < 4; tt++) {
        if (tt < ntt) {
            float* Ct = C + (size_t)(mt * 4 + tt) * V;
            #pragma unroll
            for (int j = 0; j < 2; j++) {
                const float bv = bias[col0 + j * 16];
                #pragma unroll
                for (int mi = 0; mi < 4; mi++) {
                    #pragma unroll
                    for (int r = 0; r < 4; r++) {
                        int m = mi * 16 + (lane >> 4) * 4 + r;
                        __builtin_nontemporal_store(acc[tt][j][mi][r] + bv,
                            &Ct[(size_t)m * (T * V) + col0 + j * 16]);
                    }
                }
            }
        }
    }
}

// ---------------------------------------------------------------------------
// Fused GRU gates + scores (R8-proven): one block per batch b.
// ---------------------------------------------------------------------------
__global__ __launch_bounds__(256) void gs_fused(
    const float* __restrict__ xe_t, const float* __restrict__ xm_part,
    const float* __restrict__ hm_part, const float* __restrict__ gb,
    const float* __restrict__ keys, float* __restrict__ h,
    float* __restrict__ cat2, float* __restrict__ scores, int use_xm)
{
    const int b = blockIdx.x;
    const int tid = threadIdx.x;
    __shared__ __align__(16) float hs[U];

    #pragma unroll
    for (int k = 0; k < 4; k++) {
        int u = k * 256 + tid;
        float xv[3], hv[3];
        #pragma unroll
        for (int g = 0; g < 3; g++) {
            int j = g * U + u;
            float xs = xe_t[(size_t)b * U3 + j] + gb[j];
            float hsum = gb[U3 + j];
            if (use_xm) {
                #pragma unroll
                for (int p = 0; p < 4; p++)
                    xs += xm_part[((size_t)p * 64 + b) * U3 + j];
            }
            #pragma unroll
            for (int p = 0; p < 4; p++)
                hsum += hm_part[((size_t)p * 64 + b) * U3 + j];
            xv[g] = xs; hv[g] = hsum;
        }
        float z = 1.f / (1.f + expf(-(xv[0] + hv[0])));
        float r = 1.f / (1.f + expf(-(xv[1] + hv[1])));
        float hh = tanhf(xv[2] + r * hv[2]);
        float hn = z * h[(size_t)b * U + u] + (1.f - z) * hh;
        h[(size_t)b * U + u] = hn;
        hs[u] = hn;
        cat2[(size_t)b * 2 * U + u] = hn;
    }
    __syncthreads();

    const int wave = tid >> 6, lane = tid & 63;
    for (int s = wave; s < S; s += 4) {
        const float* kr = keys + ((size_t)b * S + s) * U;
        float acc = 0.f;
        #pragma unroll
        for (int c = 0; c < 4; c++) {
            int off = c * 256 + lane * 4;
            float4 kv = *(const float4*)(kr + off);
            float4 hv4 = *(const float4*)(hs + off);
            acc += kv.x * hv4.x + kv.y * hv4.y + kv.z * hv4.z + kv.w * hv4.w;
        }
        #pragma unroll
        for (int off = 32; off > 0; off >>= 1) acc += __shfl_down(acc, off);
        if (lane == 0) scores[b * S + s] = acc;
    }
}

// softmax + context (cat2 second half); grid (B, U/256) — R8-proven
__global__ __launch_bounds__(256) void ctxcat2_kernel(
    const float* __restrict__ scores, const float* __restrict__ memory,
    float* __restrict__ cat2)
{
    const int b = blockIdx.x;
    const int u = blockIdx.y * 256 + threadIdx.x;
    __shared__ float p[S];
    __shared__ float pn[S];
    if (threadIdx.x < S) p[threadIdx.x] = scores[b * S + threadIdx.x];
    __syncthreads();
    float m = -1e30f;
    #pragma unroll 8
    for (int s = 0; s < S; s++) m = fmaxf(m, p[s]);
    float sum = 0.f;
    #pragma unroll 8
    for (int s = 0; s < S; s++) sum += expf(p[s] - m);
    if (threadIdx.x < S) pn[threadIdx.x] = expf(p[threadIdx.x] - m) / sum;
    __syncthreads();
    float acc = 0.f;
    #pragma unroll 8
    for (int s = 0; s < S; s++)
        acc += pn[s] * memory[((size_t)b * S + s) * U + u];
    cat2[(size_t)b * 2 * U + U + u] = acc;
}

// attnv_all[t] = sum8(attn_part)
__global__ __launch_bounds__(256) void reduce_attnv(
    const float* __restrict__ attn_part, float* __restrict__ dst)
{
    int idx = blockIdx.x * 256 + threadIdx.x;   // B*U
    float s = 0.f;
    #pragma unroll
    for (int p = 0; p < 8; p++) s += attn_part[(size_t)p * B * U + idx];
    dst[idx] = s;
}

// ---------------------------------------------------------------------------
extern "C" void kernel_launch(void* const* d_in, const int* in_sizes, int n_in,
                              void* d_out, int out_size, void* d_ws, size_t ws_size,
                              hipStream_t stream)
{
    const int*   x      = (const int*)  d_in[0];
    const float* enc    = (const float*)d_in[1];
    const float* memory = (const float*)d_in[2];
    const float* emb    = (const float*)d_in[3];
    const float* gk     = (const float*)d_in[4];
    const float* grk    = (const float*)d_in[5];
    const float* gb     = (const float*)d_in[6];
    const float* memW   = (const float*)d_in[7];
    const float* attnW  = (const float*)d_in[8];
    const float* fcW    = (const float*)d_in[9];
    const float* fcb    = (const float*)d_in[10];
    float* out = (float*)d_out;

    char* p = (char*)d_ws;
    auto alloc = [&](size_t bytes) { char* r = p; p += (bytes + 255) & ~(size_t)255; return r; };
    ushortT* fcWp      = (ushortT*)alloc((size_t)U * V * 2);
    float*   keys      = (float*)  alloc((size_t)B * S * U * 4);
    float*   xe        = (float*)  alloc((size_t)T * B * U3 * 4);
    float*   xm_part   = (float*)  alloc((size_t)4 * B * U3 * 4);
    float*   hm_part   = (float*)  alloc((size_t)4 * B * U3 * 4);
    float*   attn_part = (float*)  alloc((size_t)8 * B * U * 4);
    float*   h         = (float*)  alloc((size_t)B * U * 4);
    float*   attnv_all = (float*)  alloc((size_t)T * B * U * 4);
    float*   cat2      = (float*)  alloc((size_t)B * 2 * U * 4);
    float*   scores    = (float*)  alloc((size_t)B * S * 4);
    ushortT* gkp       = (ushortT*)alloc((size_t)KXM * U3 * 2 * 3);
    ushortT* grkp      = (ushortT*)alloc((size_t)U * U3 * 2 * 3);
    ushortT* awp       = (ushortT*)alloc((size_t)2 * U * U * 2 * 3);
    ushortT* mwp       = (ushortT*)alloc((size_t)U * U * 2 * 3);
    const bool PS = (size_t)(p - (char*)d_ws) <= ws_size;

    dim3 blk(256);

    if (PS) {
        pack_w3<<<(size_t)KXM * U3 / 8 / 256, blk, 0, stream>>>(gk, gkp, U3, KXM);
        pack_w3<<<(size_t)U * U3 / 8 / 256, blk, 0, stream>>>(grk, grkp, U3, U);
        pack_w3<<<(size_t)2 * U * U / 8 / 256, blk, 0, stream>>>(attnW, awp, U, 2 * U);
        pack_w3<<<(size_t)U * U / 8 / 256, blk, 0, stream>>>(memW, mwp, U, U);
    }
    pack_w<<<(size_t)U * V / 8 / 256, blk, 0, stream>>>(fcW, fcWp, V, U);
    (void)hipMemcpyAsync(h, enc, (size_t)B * U * sizeof(float),
                         hipMemcpyDeviceToDevice, stream);

    if (PS) gemm_xe<true><<<dim3(U3 / 64, T), blk, 0, stream>>>(x, emb, gk, gkp, xe);
    else    gemm_xe<false><<<dim3(U3 / 64, T), blk, 0, stream>>>(x, emb, gk, gkp, xe);

    if (PS) gemm_keys<true><<<dim3(U / 128, B * S / 64), blk, 0, stream>>>(memory, memW, mwp, keys);
    else    gemm_keys<false><<<dim3(U / 128, B * S / 64), blk, 0, stream>>>(memory, memW, mwp, keys);

    GemmJob job_hm = { h,    grk,   grkp, (size_t)U * U3,    0, 32, hm_part,   U };
    GemmJob job_at = { cat2, attnW, awp,  (size_t)2 * U * U, 0, 64, attn_part, 2 * U };

    for (int t = 0; t < T; t++) {
        GemmJob job_xm = { attnv_all + (size_t)(t - 1) * B * U, gk, gkp,
                           (size_t)KXM * U3, 8, 40, xm_part, U };
        dim3 g1(U3 / 64, 4, t > 0 ? 2 : 1);
        if (PS) gemm6_ks2<true><<<g1, blk, 0, stream>>>(job_hm, job_xm, U3, 8);
        else    gemm6_ks2<false><<<g1, blk, 0, stream>>>(job_hm, job_xm, U3, 8);
        gs_fused<<<B, blk, 0, stream>>>(
            xe + (size_t)t * B * U3, xm_part, hm_part, gb, keys, h, cat2,
            scores, t > 0 ? 1 : 0);
        ctxcat2_kernel<<<dim3(B, U / 256), blk, 0, stream>>>(scores, memory, cat2);
        dim3 g2(U / 64, 8, 1);
        if (PS) gemm6_ks2<true><<<g2, blk, 0, stream>>>(job_at, job_at, U, 8);
        else    gemm6_ks2<false><<<g2, blk, 0, stream>>>(job_at, job_at, U, 8);
        reduce_attnv<<<B * U / 256, blk, 0, stream>>>(
            attn_part, attnv_all + (size_t)t * B * U);
    }

    // all logits at once: [T*64, U] @ [U, V] + fcb (M-tile 256, XCD-pinned)
    gemm_fcB<<<32 * 5 * 8, blk, 0, stream>>>(attnv_all, fcWp, fcb, out);
}

// Round 13
// 1501.629 us; speedup vs baseline: 1.6436x; 1.0429x over previous
//
#include <hip/hip_runtime.h>
#include <hip/hip_bf16.h>
#include <math.h>

#define B 64
#define T 19
#define S 80
#define V 32000
#define E 256
#define U 1024
#define U3 (3*U)        // 3072
#define KXM (E+U)       // 1280

typedef unsigned short ushortT;
typedef __attribute__((ext_vector_type(8))) __bf16 bf16x8;
typedef __attribute__((ext_vector_type(4))) float f32x4;

__device__ __forceinline__ ushortT f2bf(float f) {
    unsigned int u = __float_as_uint(f);
    u = (u + 0x7FFF + ((u >> 16) & 1)) >> 16;   // RNE
    return (ushortT)u;
}
__device__ __forceinline__ float bf2f(ushortT u) {
    return __uint_as_float(((unsigned int)u) << 16);
}
__device__ __forceinline__ void split3(float v, ushortT& hi, ushortT& mid, ushortT& lo) {
    hi = f2bf(v);
    float r1 = v - bf2f(hi);
    mid = f2bf(r1);
    float r2 = r1 - bf2f(mid);
    lo = f2bf(r2);
}

// ---------------------------------------------------------------------------
// Pre-split weight pack: W fp32 [K][N] -> 3 bf16 planes in MFMA fragment order
// ---------------------------------------------------------------------------
__global__ __launch_bounds__(256) void pack_w3(
    const float* __restrict__ W, ushortT* __restrict__ Wp, int N, int K)
{
    int idx = blockIdx.x * 256 + threadIdx.x;
    int lane = idx & 63;
    int t = idx >> 6;
    int KC = K >> 5;
    int ntile = t / KC, kc = t - ntile * KC;
    int col = ntile * 16 + (lane & 15);
    int krow = kc * 32 + (lane >> 4) * 8;
    ushortT hi[8], mi[8], lo[8];
    #pragma unroll
    for (int i = 0; i < 8; i++)
        split3(W[(size_t)(krow + i) * N + col], hi[i], mi[i], lo[i]);
    size_t ps = (size_t)K * N;
    *(uint4*)(Wp + (size_t)idx * 8)          = *(uint4*)hi;
    *(uint4*)(Wp + ps + (size_t)idx * 8)     = *(uint4*)mi;
    *(uint4*)(Wp + 2 * ps + (size_t)idx * 8) = *(uint4*)lo;
}

// fc pack (single bf16, proven)
__global__ __launch_bounds__(256) void pack_w(
    const float* __restrict__ W, ushortT* __restrict__ Wp, int N, int K)
{
    int idx = blockIdx.x * 256 + threadIdx.x;
    int lane = idx & 63;
    int t = idx >> 6;
    int KC = K >> 5;
    int ntile = t / KC, kc = t - ntile * KC;
    int col = ntile * 16 + (lane & 15);
    int krow = kc * 32 + (lane >> 4) * 8;
    ushortT tmp[8];
    #pragma unroll
    for (int i = 0; i < 8; i++)
        tmp[i] = f2bf(W[(size_t)(krow + i) * N + col]);
    *(uint4*)(Wp + (size_t)idx * 8) = *(uint4*)tmp;
}

// ---------------------------------------------------------------------------
// Unified per-step split6 GEMM with K-split and 2-job fusion (blockIdx.z).
// (R10-proven version.)
// ---------------------------------------------------------------------------
struct GemmJob {
    const float*   A;
    const float*   W;
    const ushortT* Wp;
    unsigned long long ps;
    int kc_base;
    int KCtot;
    float* Cpart;
    int lda;
};

template<bool PRESPLIT>
__global__ __launch_bounds__(256) void gemm6_ks2(
    GemmJob j0, GemmJob j1, int N, int nkc)
{
    const int tid = threadIdx.x;
    const int lane = tid & 63;
    const int wave = tid >> 6;
    const GemmJob J = blockIdx.z ? j1 : j0;
    const int ks = blockIdx.y;
    const int ntile = blockIdx.x * 4 + wave;
    const int col = ntile * 16 + (lane & 15);
    const int kfrag = (lane >> 4) * 8;

    __shared__ __align__(16) ushortT Ahi[2048];
    __shared__ __align__(16) ushortT Amid[2048];
    __shared__ __align__(16) ushortT Alo[2048];

    f32x4 acc[4] = {};
    const int arow = (tid >> 6) * 16 + (tid & 15);
    const int kgof = ((tid >> 4) & 3) * 8;

    for (int c = 0; c < nkc; c++) {
        const int kc = ks * nkc + c;
        const float* ar = J.A + (size_t)arow * J.lda + kc * 32 + kgof;
        float av[8];
        *(float4*)(av)     = *(const float4*)(ar);
        *(float4*)(av + 4) = *(const float4*)(ar + 4);
        ushortT thi[8], tmi[8], tlo[8];
        #pragma unroll
        for (int i = 0; i < 8; i++) split3(av[i], thi[i], tmi[i], tlo[i]);
        ((uint4*)Ahi)[tid]  = *(const uint4*)thi;
        ((uint4*)Amid)[tid] = *(const uint4*)tmi;
        ((uint4*)Alo)[tid]  = *(const uint4*)tlo;

        bf16x8 bh, bm, bl;
        if constexpr (PRESPLIT) {
            size_t fi = (((size_t)ntile * J.KCtot + (J.kc_base + kc)) * 64 + lane) * 8;
            bh = *(const bf16x8*)(J.Wp + fi);
            bm = *(const bf16x8*)(J.Wp + J.ps + fi);
            bl = *(const bf16x8*)(J.Wp + 2 * J.ps + fi);
        } else {
            const float* wp = J.W + (size_t)((J.kc_base + kc) * 32 + kfrag) * N + col;
            ushortT whi[8], wmi[8], wlo[8];
            #pragma unroll
            for (int i = 0; i < 8; i++)
                split3(wp[(size_t)i * N], whi[i], wmi[i], wlo[i]);
            bh = *(const bf16x8*)whi;
            bm = *(const bf16x8*)wmi;
            bl = *(const bf16x8*)wlo;
        }

        __syncthreads();
        #pragma unroll
        for (int mi = 0; mi < 4; mi++) {
            bf16x8 ah = *(const bf16x8*)(Ahi  + (mi * 64 + lane) * 8);
            bf16x8 am = *(const bf16x8*)(Amid + (mi * 64 + lane) * 8);
            bf16x8 al = *(const bf16x8*)(Alo  + (mi * 64 + lane) * 8);
            acc[mi] = __builtin_amdgcn_mfma_f32_16x16x32_bf16(ah, bh, acc[mi], 0, 0, 0);
            acc[mi] = __builtin_amdgcn_mfma_f32_16x16x32_bf16(am, bh, acc[mi], 0, 0, 0);
            acc[mi] = __builtin_amdgcn_mfma_f32_16x16x32_bf16(ah, bm, acc[mi], 0, 0, 0);
            acc[mi] = __builtin_amdgcn_mfma_f32_16x16x32_bf16(am, bm, acc[mi], 0, 0, 0);
            acc[mi] = __builtin_amdgcn_mfma_f32_16x16x32_bf16(al, bh, acc[mi], 0, 0, 0);
            acc[mi] = __builtin_amdgcn_mfma_f32_16x16x32_bf16(ah, bl, acc[mi], 0, 0, 0);
        }
        __syncthreads();
    }

    float* cp = J.Cpart + (size_t)ks * 64 * N;
    #pragma unroll
    for (int mi = 0; mi < 4; mi++) {
        #pragma unroll
        for (int r = 0; r < 4; r++) {
            int m = mi * 16 + (lane >> 4) * 4 + r;
            cp[(size_t)m * N + col] = acc[mi][r];
        }
    }
}

// ---------------------------------------------------------------------------
// keys = memory @ mem_W: 2 n-tiles per wave, grid (U/128, B*S/64).
// ---------------------------------------------------------------------------
template<bool PRESPLIT>
__global__ __launch_bounds__(256) void gemm_keys(
    const float* __restrict__ A, const float* __restrict__ W,
    const ushortT* __restrict__ Wp, float* __restrict__ C)
{
    const int tid = threadIdx.x;
    const int lane = tid & 63;
    const int wave = tid >> 6;
    const int row0 = blockIdx.y * 64;
    const int nt0 = blockIdx.x * 8 + wave * 2;
    const int col0 = nt0 * 16 + (lane & 15);
    const int kfrag = (lane >> 4) * 8;

    __shared__ __align__(16) ushortT Ahi[2048];
    __shared__ __align__(16) ushortT Amid[2048];
    __shared__ __align__(16) ushortT Alo[2048];

    f32x4 acc[2][4] = {};
    const int arow = row0 + (tid >> 6) * 16 + (tid & 15);
    const int kgof = ((tid >> 4) & 3) * 8;
    const size_t ps = (size_t)U * U;

    for (int kc = 0; kc < 32; kc++) {
        const float* ar = A + (size_t)arow * U + kc * 32 + kgof;
        float av[8];
        *(float4*)(av)     = *(const float4*)(ar);
        *(float4*)(av + 4) = *(const float4*)(ar + 4);
        ushortT thi[8], tmi[8], tlo[8];
        #pragma unroll
        for (int i = 0; i < 8; i++) split3(av[i], thi[i], tmi[i], tlo[i]);
        ((uint4*)Ahi)[tid]  = *(const uint4*)thi;
        ((uint4*)Amid)[tid] = *(const uint4*)tmi;
        ((uint4*)Alo)[tid]  = *(const uint4*)tlo;

        bf16x8 bh[2], bm[2], bl[2];
        #pragma unroll
        for (int j = 0; j < 2; j++) {
            if constexpr (PRESPLIT) {
                size_t fi = (((size_t)(nt0 + j) * 32 + kc) * 64 + lane) * 8;
                bh[j] = *(const bf16x8*)(Wp + fi);
                bm[j] = *(const bf16x8*)(Wp + ps + fi);
                bl[j] = *(const bf16x8*)(Wp + 2 * ps + fi);
            } else {
                const float* wp = W + (size_t)(kc * 32 + kfrag) * U + col0 + j * 16;
                ushortT whi[8], wmi[8], wlo[8];
                #pragma unroll
                for (int i = 0; i < 8; i++)
                    split3(wp[(size_t)i * U], whi[i], wmi[i], wlo[i]);
                bh[j] = *(const bf16x8*)whi;
                bm[j] = *(const bf16x8*)wmi;
                bl[j] = *(const bf16x8*)wlo;
            }
        }

        __syncthreads();
        #pragma unroll
        for (int mi = 0; mi < 4; mi++) {
            bf16x8 ah = *(const bf16x8*)(Ahi  + (mi * 64 + lane) * 8);
            bf16x8 am = *(const bf16x8*)(Amid + (mi * 64 + lane) * 8);
            bf16x8 al = *(const bf16x8*)(Alo  + (mi * 64 + lane) * 8);
            #pragma unroll
            for (int j = 0; j < 2; j++) {
                acc[j][mi] = __builtin_amdgcn_mfma_f32_16x16x32_bf16(ah, bh[j], acc[j][mi], 0, 0, 0);
                acc[j][mi] = __builtin_amdgcn_mfma_f32_16x16x32_bf16(am, bh[j], acc[j][mi], 0, 0, 0);
                acc[j][mi] = __builtin_amdgcn_mfma_f32_16x16x32_bf16(ah, bm[j], acc[j][mi], 0, 0, 0);
                acc[j][mi] = __builtin_amdgcn_mfma_f32_16x16x32_bf16(am, bm[j], acc[j][mi], 0, 0, 0);
                acc[j][mi] = __builtin_amdgcn_mfma_f32_16x16x32_bf16(al, bh[j], acc[j][mi], 0, 0, 0);
                acc[j][mi] = __builtin_amdgcn_mfma_f32_16x16x32_bf16(ah, bl[j], acc[j][mi], 0, 0, 0);
            }
        }
        __syncthreads();
    }

    #pragma unroll
    for (int mi = 0; mi < 4; mi++) {
        #pragma unroll
        for (int r = 0; r < 4; r++) {
            int m = row0 + mi * 16 + (lane >> 4) * 4 + r;
            #pragma unroll
            for (int j = 0; j < 2; j++)
                C[(size_t)m * U + col0 + j * 16] = acc[j][mi][r];
        }
    }
}

// ---------------------------------------------------------------------------
// xe[t] = emb[x[:,t]] @ gk[0:256,:]   grid (U3/64, T)
// ---------------------------------------------------------------------------
template<bool PRESPLIT>
__global__ __launch_bounds__(256) void gemm_xe(
    const int* __restrict__ x, const float* __restrict__ emb,
    const float* __restrict__ gk, const ushortT* __restrict__ gkp,
    float* __restrict__ xe)
{
    const int tid = threadIdx.x;
    const int lane = tid & 63;
    const int wave = tid >> 6;
    const int t = blockIdx.y;
    const int ntile = blockIdx.x * 4 + wave;
    const int col = ntile * 16 + (lane & 15);
    const int kfrag = (lane >> 4) * 8;

    __shared__ __align__(16) ushortT Ahi[2048];
    __shared__ __align__(16) ushortT Amid[2048];
    __shared__ __align__(16) ushortT Alo[2048];

    f32x4 acc[4] = {};
    const int b = (tid >> 6) * 16 + (tid & 15);
    const int tok = x[b * T + t];
    const int kgof = ((tid >> 4) & 3) * 8;
    const size_t ps = (size_t)KXM * U3;

    for (int kc = 0; kc < E / 32; kc++) {
        const float* ar = emb + (size_t)tok * E + kc * 32 + kgof;
        float av[8];
        *(float4*)(av)     = *(const float4*)(ar);
        *(float4*)(av + 4) = *(const float4*)(ar + 4);
        ushortT thi[8], tmi[8], tlo[8];
        #pragma unroll
        for (int i = 0; i < 8; i++) split3(av[i], thi[i], tmi[i], tlo[i]);
        ((uint4*)Ahi)[tid]  = *(const uint4*)thi;
        ((uint4*)Amid)[tid] = *(const uint4*)tmi;
        ((uint4*)Alo)[tid]  = *(const uint4*)tlo;

        bf16x8 bh, bm, bl;
        if constexpr (PRESPLIT) {
            size_t fi = (((size_t)ntile * 40 + kc) * 64 + lane) * 8;   // gk KCtot=40
            bh = *(const bf16x8*)(gkp + fi);
            bm = *(const bf16x8*)(gkp + ps + fi);
            bl = *(const bf16x8*)(gkp + 2 * ps + fi);
        } else {
            const float* wp = gk + (size_t)(kc * 32 + kfrag) * U3 + col;
            ushortT whi[8], wmi[8], wlo[8];
            #pragma unroll
            for (int i = 0; i < 8; i++)
                split3(wp[(size_t)i * U3], whi[i], wmi[i], wlo[i]);
            bh = *(const bf16x8*)whi;
            bm = *(const bf16x8*)wmi;
            bl = *(const bf16x8*)wlo;
        }

        __syncthreads();
        #pragma unroll
        for (int mi = 0; mi < 4; mi++) {
            bf16x8 ah = *(const bf16x8*)(Ahi  + (mi * 64 + lane) * 8);
            bf16x8 am = *(const bf16x8*)(Amid + (mi * 64 + lane) * 8);
            bf16x8 al = *(const bf16x8*)(Alo  + (mi * 64 + lane) * 8);
            acc[mi] = __builtin_amdgcn_mfma_f32_16x16x32_bf16(ah, bh, acc[mi], 0, 0, 0);
            acc[mi] = __builtin_amdgcn_mfma_f32_16x16x32_bf16(am, bh, acc[mi], 0, 0, 0);
            acc[mi] = __builtin_amdgcn_mfma_f32_16x16x32_bf16(ah, bm, acc[mi], 0, 0, 0);
            acc[mi] = __builtin_amdgcn_mfma_f32_16x16x32_bf16(am, bm, acc[mi], 0, 0, 0);
            acc[mi] = __builtin_amdgcn_mfma_f32_16x16x32_bf16(al, bh, acc[mi], 0, 0, 0);
            acc[mi] = __builtin_amdgcn_mfma_f32_16x16x32_bf16(ah, bl, acc[mi], 0, 0, 0);
        }
        __syncthreads();
    }

    #pragma unroll
    for (int mi = 0; mi < 4; mi++) {
        #pragma unroll
        for (int r = 0; r < 4; r++) {
            int m = mi * 16 + (lane >> 4) * 4 + r;
            xe[((size_t)t * 64 + m) * U3 + col] = acc[mi][r];
        }
    }
}

// ---------------------------------------------------------------------------
// Batched fc GEMM v5: M-tile 128 (2 t-groups/block) — occupancy/reuse midpoint
// between R10 (M64: occ 41%, FETCH 332MB, 216us) and R12 (M256: occ 11%,
// FETCH 133MB, 297us). acc[2][2][4]=64 VGPRs, LDS 16KB. XCD-pinned mt-major:
// bid=(g*10+mt)*8+x, strip=g*8+x. All-static acc indexing (no spill).
// ---------------------------------------------------------------------------
__global__ __launch_bounds__(256) void gemm_fcB(
    const float* __restrict__ A, const ushortT* __restrict__ Wp,
    const float* __restrict__ bias, float* __restrict__ C)
{
    const int xcd = blockIdx.x & 7;
    const int rem = blockIdx.x >> 3;        // g*10 + mt
    const int g = rem / 10;
    const int mt = rem - g * 10;
    const int strip = g * 8 + xcd;
    if (strip >= V / 128) return;
    const int ntt = (mt == 9) ? 1 : 2;      // T = 19 = 9*2 + 1

    const int tid = threadIdx.x;
    const int lane = tid & 63;
    const int wave = tid >> 6;
    const int nt0 = strip * 8 + wave * 2;
    const int col0 = nt0 * 16 + (lane & 15);

    __shared__ __align__(16) ushortT As[2][2][2048];   // 16 KB

    f32x4 acc[2][2][4] = {};                // [tt][j][mi] — all static indexing
    const int arow = (tid >> 6) * 16 + (tid & 15);
    const int kgof = ((tid >> 4) & 3) * 8;

    for (int it = 0; it < 16; it++) {
        #pragma unroll
        for (int tt = 0; tt < 2; tt++) {
            if (tt < ntt) {
                #pragma unroll
                for (int c = 0; c < 2; c++) {
                    const float* ar = A + ((size_t)(mt * 2 + tt) * 64 + arow) * U
                                        + (it * 2 + c) * 32 + kgof;
                    float4 f0 = *(const float4*)(ar);
                    float4 f1 = *(const float4*)(ar + 4);
                    ushortT tmp[8] = { f2bf(f0.x), f2bf(f0.y), f2bf(f0.z), f2bf(f0.w),
                                       f2bf(f1.x), f2bf(f1.y), f2bf(f1.z), f2bf(f1.w) };
                    ((uint4*)As[tt][c])[tid] = *(const uint4*)tmp;
                }
            }
        }
        bf16x8 b[2][2];
        #pragma unroll
        for (int c = 0; c < 2; c++)
            #pragma unroll
            for (int j = 0; j < 2; j++)
                b[c][j] = *(const bf16x8*)(Wp +
                    (((size_t)(nt0 + j) * 32 + it * 2 + c) * 64 + lane) * 8);
        __syncthreads();
        #pragma unroll
        for (int tt = 0; tt < 2; tt++) {
            if (tt < ntt) {
                #pragma unroll
                for (int c = 0; c < 2; c++) {
                    #pragma unroll
                    for (int mi = 0; mi < 4; mi++) {
                        bf16x8 a = *(const bf16x8*)(&As[tt][c][(mi * 64 + lane) * 8]);
                        #pragma unroll
                        for (int j = 0; j < 2; j++)
                            acc[tt][j][mi] = __builtin_amdgcn_mfma_f32_16x16x32_bf16(
                                a, b[c][j], acc[tt][j][mi], 0, 0, 0);
                    }
                }
            }
        }
        __syncthreads();
    }

    #pragma unroll
    for (int tt = 0; tt < 2; tt++) {
        if (tt < ntt) {
            float* Ct = C + (size_t)(mt * 2 + tt) * V;
            #pragma unroll
            for (int j = 0; j < 2; j++) {
                const float bv = bias[col0 + j * 16];
                #pragma unroll
                for (int mi = 0; mi < 4; mi++) {
                    #pragma unroll
                    for (int r = 0; r < 4; r++) {
                        int m = mi * 16 + (lane >> 4) * 4 + r;
                        __builtin_nontemporal_store(acc[tt][j][mi][r] + bv,
                            &Ct[(size_t)m * (T * V) + col0 + j * 16]);
                    }
                }
            }
        }
    }
}

// ---------------------------------------------------------------------------
// Fused GRU gates + scores (R8-proven): one block per batch b.
// ---------------------------------------------------------------------------
__global__ __launch_bounds__(256) void gs_fused(
    const float* __restrict__ xe_t, const float* __restrict__ xm_part,
    const float* __restrict__ hm_part, const float* __restrict__ gb,
    const float* __restrict__ keys, float* __restrict__ h,
    float* __restrict__ cat2, float* __restrict__ scores, int use_xm)
{
    const int b = blockIdx.x;
    const int tid = threadIdx.x;
    __shared__ __align__(16) float hs[U];

    #pragma unroll
    for (int k = 0; k < 4; k++) {
        int u = k * 256 + tid;
        float xv[3], hv[3];
        #pragma unroll
        for (int g = 0; g < 3; g++) {
            int j = g * U + u;
            float xs = xe_t[(size_t)b * U3 + j] + gb[j];
            float hsum = gb[U3 + j];
            if (use_xm) {
                #pragma unroll
                for (int p = 0; p < 4; p++)
                    xs += xm_part[((size_t)p * 64 + b) * U3 + j];
            }
            #pragma unroll
            for (int p = 0; p < 4; p++)
                hsum += hm_part[((size_t)p * 64 + b) * U3 + j];
            xv[g] = xs; hv[g] = hsum;
        }
        float z = 1.f / (1.f + expf(-(xv[0] + hv[0])));
        float r = 1.f / (1.f + expf(-(xv[1] + hv[1])));
        float hh = tanhf(xv[2] + r * hv[2]);
        float hn = z * h[(size_t)b * U + u] + (1.f - z) * hh;
        h[(size_t)b * U + u] = hn;
        hs[u] = hn;
        cat2[(size_t)b * 2 * U + u] = hn;
    }
    __syncthreads();

    const int wave = tid >> 6, lane = tid & 63;
    for (int s = wave; s < S; s += 4) {
        const float* kr = keys + ((size_t)b * S + s) * U;
        float acc = 0.f;
        #pragma unroll
        for (int c = 0; c < 4; c++) {
            int off = c * 256 + lane * 4;
            float4 kv = *(const float4*)(kr + off);
            float4 hv4 = *(const float4*)(hs + off);
            acc += kv.x * hv4.x + kv.y * hv4.y + kv.z * hv4.z + kv.w * hv4.w;
        }
        #pragma unroll
        for (int off = 32; off > 0; off >>= 1) acc += __shfl_down(acc, off);
        if (lane == 0) scores[b * S + s] = acc;
    }
}

// softmax + context (cat2 second half); grid (B, U/256) — R8-proven
__global__ __launch_bounds__(256) void ctxcat2_kernel(
    const float* __restrict__ scores, const float* __restrict__ memory,
    float* __restrict__ cat2)
{
    const int b = blockIdx.x;
    const int u = blockIdx.y * 256 + threadIdx.x;
    __shared__ float p[S];
    __shared__ float pn[S];
    if (threadIdx.x < S) p[threadIdx.x] = scores[b * S + threadIdx.x];
    __syncthreads();
    float m = -1e30f;
    #pragma unroll 8
    for (int s = 0; s < S; s++) m = fmaxf(m, p[s]);
    float sum = 0.f;
    #pragma unroll 8
    for (int s = 0; s < S; s++) sum += expf(p[s] - m);
    if (threadIdx.x < S) pn[threadIdx.x] = expf(p[threadIdx.x] - m) / sum;
    __syncthreads();
    float acc = 0.f;
    #pragma unroll 8
    for (int s = 0; s < S; s++)
        acc += pn[s] * memory[((size_t)b * S + s) * U + u];
    cat2[(size_t)b * 2 * U + U + u] = acc;
}

// attnv_all[t] = sum8(attn_part)
__global__ __launch_bounds__(256) void reduce_attnv(
    const float* __restrict__ attn_part, float* __restrict__ dst)
{
    int idx = blockIdx.x * 256 + threadIdx.x;   // B*U
    float s = 0.f;
    #pragma unroll
    for (int p = 0; p < 8; p++) s += attn_part[(size_t)p * B * U + idx];
    dst[idx] = s;
}

// ---------------------------------------------------------------------------
extern "C" void kernel_launch(void* const* d_in, const int* in_sizes, int n_in,
                              void* d_out, int out_size, void* d_ws, size_t ws_size,
                              hipStream_t stream)
{
    const int*   x      = (const int*)  d_in[0];
    const float* enc    = (const float*)d_in[1];
    const float* memory = (const float*)d_in[2];
    const float* emb    = (const float*)d_in[3];
    const float* gk     = (const float*)d_in[4];
    const float* grk    = (const float*)d_in[5];
    const float* gb     = (const float*)d_in[6];
    const float* memW   = (const float*)d_in[7];
    const float* attnW  = (const float*)d_in[8];
    const float* fcW    = (const float*)d_in[9];
    const float* fcb    = (const float*)d_in[10];
    float* out = (float*)d_out;

    char* p = (char*)d_ws;
    auto alloc = [&](size_t bytes) { char* r = p; p += (bytes + 255) & ~(size_t)255; return r; };
    ushortT* fcWp      = (ushortT*)alloc((size_t)U * V * 2);
    float*   keys      = (float*)  alloc((size_t)B * S * U * 4);
    float*   xe        = (float*)  alloc((size_t)T * B * U3 * 4);
    float*   xm_part   = (float*)  alloc((size_t)4 * B * U3 * 4);
    float*   hm_part   = (float*)  alloc((size_t)4 * B * U3 * 4);
    float*   attn_part = (float*)  alloc((size_t)8 * B * U * 4);
    float*   h         = (float*)  alloc((size_t)B * U * 4);
    float*   attnv_all = (float*)  alloc((size_t)T * B * U * 4);
    float*   cat2      = (float*)  alloc((size_t)B * 2 * U * 4);
    float*   scores    = (float*)  alloc((size_t)B * S * 4);
    ushortT* gkp       = (ushortT*)alloc((size_t)KXM * U3 * 2 * 3);
    ushortT* grkp      = (ushortT*)alloc((size_t)U * U3 * 2 * 3);
    ushortT* awp       = (ushortT*)alloc((size_t)2 * U * U * 2 * 3);
    ushortT* mwp       = (ushortT*)alloc((size_t)U * U * 2 * 3);
    const bool PS = (size_t)(p - (char*)d_ws) <= ws_size;

    dim3 blk(256);

    if (PS) {
        pack_w3<<<(size_t)KXM * U3 / 8 / 256, blk, 0, stream>>>(gk, gkp, U3, KXM);
        pack_w3<<<(size_t)U * U3 / 8 / 256, blk, 0, stream>>>(grk, grkp, U3, U);
        pack_w3<<<(size_t)2 * U * U / 8 / 256, blk, 0, stream>>>(attnW, awp, U, 2 * U);
        pack_w3<<<(size_t)U * U / 8 / 256, blk, 0, stream>>>(memW, mwp, U, U);
    }
    pack_w<<<(size_t)U * V / 8 / 256, blk, 0, stream>>>(fcW, fcWp, V, U);
    (void)hipMemcpyAsync(h, enc, (size_t)B * U * sizeof(float),
                         hipMemcpyDeviceToDevice, stream);

    if (PS) gemm_xe<true><<<dim3(U3 / 64, T), blk, 0, stream>>>(x, emb, gk, gkp, xe);
    else    gemm_xe<false><<<dim3(U3 / 64, T), blk, 0, stream>>>(x, emb, gk, gkp, xe);

    if (PS) gemm_keys<true><<<dim3(U / 128, B * S / 64), blk, 0, stream>>>(memory, memW, mwp, keys);
    else    gemm_keys<false><<<dim3(U / 128, B * S / 64), blk, 0, stream>>>(memory, memW, mwp, keys);

    GemmJob job_hm = { h,    grk,   grkp, (size_t)U * U3,    0, 32, hm_part,   U };
    GemmJob job_at = { cat2, attnW, awp,  (size_t)2 * U * U, 0, 64, attn_part, 2 * U };

    for (int t = 0; t < T; t++) {
        GemmJob job_xm = { attnv_all + (size_t)(t - 1) * B * U, gk, gkp,
                           (size_t)KXM * U3, 8, 40, xm_part, U };
        dim3 g1(U3 / 64, 4, t > 0 ? 2 : 1);
        if (PS) gemm6_ks2<true><<<g1, blk, 0, stream>>>(job_hm, job_xm, U3, 8);
        else    gemm6_ks2<false><<<g1, blk, 0, stream>>>(job_hm, job_xm, U3, 8);
        gs_fused<<<B, blk, 0, stream>>>(
            xe + (size_t)t * B * U3, xm_part, hm_part, gb, keys, h, cat2,
            scores, t > 0 ? 1 : 0);
        ctxcat2_kernel<<<dim3(B, U / 256), blk, 0, stream>>>(scores, memory, cat2);
        dim3 g2(U / 64, 8, 1);
        if (PS) gemm6_ks2<true><<<g2, blk, 0, stream>>>(job_at, job_at, U, 8);
        else    gemm6_ks2<false><<<g2, blk, 0, stream>>>(job_at, job_at, U, 8);
        reduce_attnv<<<B * U / 256, blk, 0, stream>>>(
            attn_part, attnv_all + (size_t)t * B * U);
    }

    // all logits at once: [T*64, U] @ [U, V] + fcb (M-tile 128, XCD-pinned)
    gemm_fcB<<<32 * 10 * 8, blk, 0, stream>>>(attnv_all, fcWp, fcb, out);
}

// Round 14
// 1396.122 us; speedup vs baseline: 1.7678x; 1.0756x over previous
//
#include <hip/hip_runtime.h>
#include <hip/hip_bf16.h>
#include <math.h>

#define B 64
#define T 19
#define S 80
#define V 32000
#define E 256
#define U 1024
#define U3 (3*U)        // 3072
#define KXM (E+U)       // 1280

typedef unsigned short ushortT;
typedef __attribute__((ext_vector_type(8))) __bf16 bf16x8;
typedef __attribute__((ext_vector_type(4))) float f32x4;

__device__ __forceinline__ ushortT f2bf(float f) {
    unsigned int u = __float_as_uint(f);
    u = (u + 0x7FFF + ((u >> 16) & 1)) >> 16;   // RNE
    return (ushortT)u;
}
__device__ __forceinline__ float bf2f(ushortT u) {
    return __uint_as_float(((unsigned int)u) << 16);
}
__device__ __forceinline__ void split3(float v, ushortT& hi, ushortT& mid, ushortT& lo) {
    hi = f2bf(v);
    float r1 = v - bf2f(hi);
    mid = f2bf(r1);
    float r2 = r1 - bf2f(mid);
    lo = f2bf(r2);
}

// ---------------------------------------------------------------------------
// Pre-split weight pack: W fp32 [K][N] -> 3 bf16 planes in MFMA fragment order
// ---------------------------------------------------------------------------
__global__ __launch_bounds__(256) void pack_w3(
    const float* __restrict__ W, ushortT* __restrict__ Wp, int N, int K)
{
    int idx = blockIdx.x * 256 + threadIdx.x;
    int lane = idx & 63;
    int t = idx >> 6;
    int KC = K >> 5;
    int ntile = t / KC, kc = t - ntile * KC;
    int col = ntile * 16 + (lane & 15);
    int krow = kc * 32 + (lane >> 4) * 8;
    ushortT hi[8], mi[8], lo[8];
    #pragma unroll
    for (int i = 0; i < 8; i++)
        split3(W[(size_t)(krow + i) * N + col], hi[i], mi[i], lo[i]);
    size_t ps = (size_t)K * N;
    *(uint4*)(Wp + (size_t)idx * 8)          = *(uint4*)hi;
    *(uint4*)(Wp + ps + (size_t)idx * 8)     = *(uint4*)mi;
    *(uint4*)(Wp + 2 * ps + (size_t)idx * 8) = *(uint4*)lo;
}

// fc pack (single bf16, proven)
__global__ __launch_bounds__(256) void pack_w(
    const float* __restrict__ W, ushortT* __restrict__ Wp, int N, int K)
{
    int idx = blockIdx.x * 256 + threadIdx.x;
    int lane = idx & 63;
    int t = idx >> 6;
    int KC = K >> 5;
    int ntile = t / KC, kc = t - ntile * KC;
    int col = ntile * 16 + (lane & 15);
    int krow = kc * 32 + (lane >> 4) * 8;
    ushortT tmp[8];
    #pragma unroll
    for (int i = 0; i < 8; i++)
        tmp[i] = f2bf(W[(size_t)(krow + i) * N + col]);
    *(uint4*)(Wp + (size_t)idx * 8) = *(uint4*)tmp;
}

// ---------------------------------------------------------------------------
// Unified per-step split6 GEMM with K-split and 2-job fusion (blockIdx.z).
// ---------------------------------------------------------------------------
struct GemmJob {
    const float*   A;
    const float*   W;
    const ushortT* Wp;
    unsigned long long ps;
    int kc_base;
    int KCtot;
    float* Cpart;
    int lda;
};

template<bool PRESPLIT>
__global__ __launch_bounds__(256) void gemm6_ks2(
    GemmJob j0, GemmJob j1, int N, int nkc)
{
    const int tid = threadIdx.x;
    const int lane = tid & 63;
    const int wave = tid >> 6;
    const GemmJob J = blockIdx.z ? j1 : j0;
    const int ks = blockIdx.y;
    const int ntile = blockIdx.x * 4 + wave;
    const int col = ntile * 16 + (lane & 15);
    const int kfrag = (lane >> 4) * 8;

    __shared__ __align__(16) ushortT Ahi[2048];
    __shared__ __align__(16) ushortT Amid[2048];
    __shared__ __align__(16) ushortT Alo[2048];

    f32x4 acc[4] = {};
    const int arow = (tid >> 6) * 16 + (tid & 15);
    const int kgof = ((tid >> 4) & 3) * 8;

    for (int c = 0; c < nkc; c++) {
        const int kc = ks * nkc + c;
        const float* ar = J.A + (size_t)arow * J.lda + kc * 32 + kgof;
        float av[8];
        *(float4*)(av)     = *(const float4*)(ar);
        *(float4*)(av + 4) = *(const float4*)(ar + 4);
        ushortT thi[8], tmi[8], tlo[8];
        #pragma unroll
        for (int i = 0; i < 8; i++) split3(av[i], thi[i], tmi[i], tlo[i]);
        ((uint4*)Ahi)[tid]  = *(const uint4*)thi;
        ((uint4*)Amid)[tid] = *(const uint4*)tmi;
        ((uint4*)Alo)[tid]  = *(const uint4*)tlo;

        bf16x8 bh, bm, bl;
        if constexpr (PRESPLIT) {
            size_t fi = (((size_t)ntile * J.KCtot + (J.kc_base + kc)) * 64 + lane) * 8;
            bh = *(const bf16x8*)(J.Wp + fi);
            bm = *(const bf16x8*)(J.Wp + J.ps + fi);
            bl = *(const bf16x8*)(J.Wp + 2 * J.ps + fi);
        } else {
            const float* wp = J.W + (size_t)((J.kc_base + kc) * 32 + kfrag) * N + col;
            ushortT whi[8], wmi[8], wlo[8];
            #pragma unroll
            for (int i = 0; i < 8; i++)
                split3(wp[(size_t)i * N], whi[i], wmi[i], wlo[i]);
            bh = *(const bf16x8*)whi;
            bm = *(const bf16x8*)wmi;
            bl = *(const bf16x8*)wlo;
        }

        __syncthreads();
        #pragma unroll
        for (int mi = 0; mi < 4; mi++) {
            bf16x8 ah = *(const bf16x8*)(Ahi  + (mi * 64 + lane) * 8);
            bf16x8 am = *(const bf16x8*)(Amid + (mi * 64 + lane) * 8);
            bf16x8 al = *(const bf16x8*)(Alo  + (mi * 64 + lane) * 8);
            acc[mi] = __builtin_amdgcn_mfma_f32_16x16x32_bf16(ah, bh, acc[mi], 0, 0, 0);
            acc[mi] = __builtin_amdgcn_mfma_f32_16x16x32_bf16(am, bh, acc[mi], 0, 0, 0);
            acc[mi] = __builtin_amdgcn_mfma_f32_16x16x32_bf16(ah, bm, acc[mi], 0, 0, 0);
            acc[mi] = __builtin_amdgcn_mfma_f32_16x16x32_bf16(am, bm, acc[mi], 0, 0, 0);
            acc[mi] = __builtin_amdgcn_mfma_f32_16x16x32_bf16(al, bh, acc[mi], 0, 0, 0);
            acc[mi] = __builtin_amdgcn_mfma_f32_16x16x32_bf16(ah, bl, acc[mi], 0, 0, 0);
        }
        __syncthreads();
    }

    float* cp = J.Cpart + (size_t)ks * 64 * N;
    #pragma unroll
    for (int mi = 0; mi < 4; mi++) {
        #pragma unroll
        for (int r = 0; r < 4; r++) {
            int m = mi * 16 + (lane >> 4) * 4 + r;
            cp[(size_t)m * N + col] = acc[mi][r];
        }
    }
}

// ---------------------------------------------------------------------------
// keys = memory @ mem_W: 2 n-tiles per wave, grid (U/128, B*S/64).
// ---------------------------------------------------------------------------
template<bool PRESPLIT>
__global__ __launch_bounds__(256) void gemm_keys(
    const float* __restrict__ A, const float* __restrict__ W,
    const ushortT* __restrict__ Wp, float* __restrict__ C)
{
    const int tid = threadIdx.x;
    const int lane = tid & 63;
    const int wave = tid >> 6;
    const int row0 = blockIdx.y * 64;
    const int nt0 = blockIdx.x * 8 + wave * 2;
    const int col0 = nt0 * 16 + (lane & 15);
    const int kfrag = (lane >> 4) * 8;

    __shared__ __align__(16) ushortT Ahi[2048];
    __shared__ __align__(16) ushortT Amid[2048];
    __shared__ __align__(16) ushortT Alo[2048];

    f32x4 acc[2][4] = {};
    const int arow = row0 + (tid >> 6) * 16 + (tid & 15);
    const int kgof = ((tid >> 4) & 3) * 8;
    const size_t ps = (size_t)U * U;

    for (int kc = 0; kc < 32; kc++) {
        const float* ar = A + (size_t)arow * U + kc * 32 + kgof;
        float av[8];
        *(float4*)(av)     = *(const float4*)(ar);
        *(float4*)(av + 4) = *(const float4*)(ar + 4);
        ushortT thi[8], tmi[8], tlo[8];
        #pragma unroll
        for (int i = 0; i < 8; i++) split3(av[i], thi[i], tmi[i], tlo[i]);
        ((uint4*)Ahi)[tid]  = *(const uint4*)thi;
        ((uint4*)Amid)[tid] = *(const uint4*)tmi;
        ((uint4*)Alo)[tid]  = *(const uint4*)tlo;

        bf16x8 bh[2], bm[2], bl[2];
        #pragma unroll
        for (int j = 0; j < 2; j++) {
            if constexpr (PRESPLIT) {
                size_t fi = (((size_t)(nt0 + j) * 32 + kc) * 64 + lane) * 8;
                bh[j] = *(const bf16x8*)(Wp + fi);
                bm[j] = *(const bf16x8*)(Wp + ps + fi);
                bl[j] = *(const bf16x8*)(Wp + 2 * ps + fi);
            } else {
                const float* wp = W + (size_t)(kc * 32 + kfrag) * U + col0 + j * 16;
                ushortT whi[8], wmi[8], wlo[8];
                #pragma unroll
                for (int i = 0; i < 8; i++)
                    split3(wp[(size_t)i * U], whi[i], wmi[i], wlo[i]);
                bh[j] = *(const bf16x8*)whi;
                bm[j] = *(const bf16x8*)wmi;
                bl[j] = *(const bf16x8*)wlo;
            }
        }

        __syncthreads();
        #pragma unroll
        for (int mi = 0; mi < 4; mi++) {
            bf16x8 ah = *(const bf16x8*)(Ahi  + (mi * 64 + lane) * 8);
            bf16x8 am = *(const bf16x8*)(Amid + (mi * 64 + lane) * 8);
            bf16x8 al = *(const bf16x8*)(Alo  + (mi * 64 + lane) * 8);
            #pragma unroll
            for (int j = 0; j < 2; j++) {
                acc[j][mi] = __builtin_amdgcn_mfma_f32_16x16x32_bf16(ah, bh[j], acc[j][mi], 0, 0, 0);
                acc[j][mi] = __builtin_amdgcn_mfma_f32_16x16x32_bf16(am, bh[j], acc[j][mi], 0, 0, 0);
                acc[j][mi] = __builtin_amdgcn_mfma_f32_16x16x32_bf16(ah, bm[j], acc[j][mi], 0, 0, 0);
                acc[j][mi] = __builtin_amdgcn_mfma_f32_16x16x32_bf16(am, bm[j], acc[j][mi], 0, 0, 0);
                acc[j][mi] = __builtin_amdgcn_mfma_f32_16x16x32_bf16(al, bh[j], acc[j][mi], 0, 0, 0);
                acc[j][mi] = __builtin_amdgcn_mfma_f32_16x16x32_bf16(ah, bl[j], acc[j][mi], 0, 0, 0);
            }
        }
        __syncthreads();
    }

    #pragma unroll
    for (int mi = 0; mi < 4; mi++) {
        #pragma unroll
        for (int r = 0; r < 4; r++) {
            int m = row0 + mi * 16 + (lane >> 4) * 4 + r;
            #pragma unroll
            for (int j = 0; j < 2; j++)
                C[(size_t)m * U + col0 + j * 16] = acc[j][mi][r];
        }
    }
}

// ---------------------------------------------------------------------------
// xe[t] = emb[x[:,t]] @ gk[0:256,:]   grid (U3/64, T)
// ---------------------------------------------------------------------------
template<bool PRESPLIT>
__global__ __launch_bounds__(256) void gemm_xe(
    const int* __restrict__ x, const float* __restrict__ emb,
    const float* __restrict__ gk, const ushortT* __restrict__ gkp,
    float* __restrict__ xe)
{
    const int tid = threadIdx.x;
    const int lane = tid & 63;
    const int wave = tid >> 6;
    const int t = blockIdx.y;
    const int ntile = blockIdx.x * 4 + wave;
    const int col = ntile * 16 + (lane & 15);
    const int kfrag = (lane >> 4) * 8;

    __shared__ __align__(16) ushortT Ahi[2048];
    __shared__ __align__(16) ushortT Amid[2048];
    __shared__ __align__(16) ushortT Alo[2048];

    f32x4 acc[4] = {};
    const int b = (tid >> 6) * 16 + (tid & 15);
    const int tok = x[b * T + t];
    const int kgof = ((tid >> 4) & 3) * 8;
    const size_t ps = (size_t)KXM * U3;

    for (int kc = 0; kc < E / 32; kc++) {
        const float* ar = emb + (size_t)tok * E + kc * 32 + kgof;
        float av[8];
        *(float4*)(av)     = *(const float4*)(ar);
        *(float4*)(av + 4) = *(const float4*)(ar + 4);
        ushortT thi[8], tmi[8], tlo[8];
        #pragma unroll
        for (int i = 0; i < 8; i++) split3(av[i], thi[i], tmi[i], tlo[i]);
        ((uint4*)Ahi)[tid]  = *(const uint4*)thi;
        ((uint4*)Amid)[tid] = *(const uint4*)tmi;
        ((uint4*)Alo)[tid]  = *(const uint4*)tlo;

        bf16x8 bh, bm, bl;
        if constexpr (PRESPLIT) {
            size_t fi = (((size_t)ntile * 40 + kc) * 64 + lane) * 8;   // gk KCtot=40
            bh = *(const bf16x8*)(gkp + fi);
            bm = *(const bf16x8*)(gkp + ps + fi);
            bl = *(const bf16x8*)(gkp + 2 * ps + fi);
        } else {
            const float* wp = gk + (size_t)(kc * 32 + kfrag) * U3 + col;
            ushortT whi[8], wmi[8], wlo[8];
            #pragma unroll
            for (int i = 0; i < 8; i++)
                split3(wp[(size_t)i * U3], whi[i], wmi[i], wlo[i]);
            bh = *(const bf16x8*)whi;
            bm = *(const bf16x8*)wmi;
            bl = *(const bf16x8*)wlo;
        }

        __syncthreads();
        #pragma unroll
        for (int mi = 0; mi < 4; mi++) {
            bf16x8 ah = *(const bf16x8*)(Ahi  + (mi * 64 + lane) * 8);
            bf16x8 am = *(const bf16x8*)(Amid + (mi * 64 + lane) * 8);
            bf16x8 al = *(const bf16x8*)(Alo  + (mi * 64 + lane) * 8);
            acc[mi] = __builtin_amdgcn_mfma_f32_16x16x32_bf16(ah, bh, acc[mi], 0, 0, 0);
            acc[mi] = __builtin_amdgcn_mfma_f32_16x16x32_bf16(am, bh, acc[mi], 0, 0, 0);
            acc[mi] = __builtin_amdgcn_mfma_f32_16x16x32_bf16(ah, bm, acc[mi], 0, 0, 0);
            acc[mi] = __builtin_amdgcn_mfma_f32_16x16x32_bf16(am, bm, acc[mi], 0, 0, 0);
            acc[mi] = __builtin_amdgcn_mfma_f32_16x16x32_bf16(al, bh, acc[mi], 0, 0, 0);
            acc[mi] = __builtin_amdgcn_mfma_f32_16x16x32_bf16(ah, bl, acc[mi], 0, 0, 0);
        }
        __syncthreads();
    }

    #pragma unroll
    for (int mi = 0; mi < 4; mi++) {
        #pragma unroll
        for (int r = 0; r < 4; r++) {
            int m = mi * 16 + (lane >> 4) * 4 + r;
            xe[((size_t)t * 64 + m) * U3 + col] = acc[mi][r];
        }
    }
}

// ---------------------------------------------------------------------------
// Batched fc GEMM (R10 M64 version — measured best at 216us): XCD-pinned,
// bid = (g*19 + t)*8 + x, strip = g*8 + x. Grid 32*19*8 = 4864.
// ---------------------------------------------------------------------------
__global__ __launch_bounds__(256) void gemm_fcB(
    const float* __restrict__ A, const ushortT* __restrict__ Wp,
    const float* __restrict__ bias, float* __restrict__ C)
{
    const int xcd = blockIdx.x & 7;
    const int rem = blockIdx.x >> 3;        // g*19 + t
    const int g = rem / T;
    const int tg = rem - g * T;
    const int strip = g * 8 + xcd;
    if (strip >= V / 128) return;

    const int tid = threadIdx.x;
    const int lane = tid & 63;
    const int wave = tid >> 6;
    const int nt0 = strip * 8 + wave * 2;
    const int col0 = nt0 * 16 + (lane & 15);

    __shared__ __align__(16) ushortT As[2][2048];

    f32x4 acc[2][4] = {};
    const int arow = (tid >> 6) * 16 + (tid & 15);
    const float* At = A + (size_t)tg * 64 * U;
    float* Ct = C + (size_t)tg * V;
    const int kgof = ((tid >> 4) & 3) * 8;

    for (int it = 0; it < 16; it++) {
        #pragma unroll
        for (int c = 0; c < 2; c++) {
            const float* ar = At + (size_t)arow * U + (it * 2 + c) * 32 + kgof;
            float4 f0 = *(const float4*)(ar);
            float4 f1 = *(const float4*)(ar + 4);
            ushortT tmp[8] = { f2bf(f0.x), f2bf(f0.y), f2bf(f0.z), f2bf(f0.w),
                               f2bf(f1.x), f2bf(f1.y), f2bf(f1.z), f2bf(f1.w) };
            ((uint4*)As[c])[tid] = *(const uint4*)tmp;
        }
        bf16x8 b[2][2];
        #pragma unroll
        for (int c = 0; c < 2; c++)
            #pragma unroll
            for (int j = 0; j < 2; j++)
                b[c][j] = *(const bf16x8*)(Wp +
                    (((size_t)(nt0 + j) * 32 + it * 2 + c) * 64 + lane) * 8);
        __syncthreads();
        #pragma unroll
        for (int c = 0; c < 2; c++) {
            #pragma unroll
            for (int mi = 0; mi < 4; mi++) {
                bf16x8 a = *(const bf16x8*)(As[c] + (mi * 64 + lane) * 8);
                #pragma unroll
                for (int j = 0; j < 2; j++)
                    acc[j][mi] = __builtin_amdgcn_mfma_f32_16x16x32_bf16(a, b[c][j], acc[j][mi], 0, 0, 0);
            }
        }
        __syncthreads();
    }

    #pragma unroll
    for (int j = 0; j < 2; j++) {
        const float bv = bias[col0 + j * 16];
        #pragma unroll
        for (int mi = 0; mi < 4; mi++) {
            #pragma unroll
            for (int r = 0; r < 4; r++) {
                int m = mi * 16 + (lane >> 4) * 4 + r;
                __builtin_nontemporal_store(acc[j][mi][r] + bv,
                    &Ct[(size_t)m * (T * V) + col0 + j * 16]);
            }
        }
    }
}

// ---------------------------------------------------------------------------
// Fused GRU gates + scores: one block per batch b. 8 k-split partials.
// ---------------------------------------------------------------------------
__global__ __launch_bounds__(256) void gs_fused(
    const float* __restrict__ xe_t, const float* __restrict__ xm_part,
    const float* __restrict__ hm_part, const float* __restrict__ gb,
    const float* __restrict__ keys, float* __restrict__ h,
    float* __restrict__ cat2, float* __restrict__ scores, int use_xm)
{
    const int b = blockIdx.x;
    const int tid = threadIdx.x;
    __shared__ __align__(16) float hs[U];

    #pragma unroll
    for (int k = 0; k < 4; k++) {
        int u = k * 256 + tid;
        float xv[3], hv[3];
        #pragma unroll
        for (int g = 0; g < 3; g++) {
            int j = g * U + u;
            float xs = xe_t[(size_t)b * U3 + j] + gb[j];
            float hsum = gb[U3 + j];
            if (use_xm) {
                #pragma unroll
                for (int p = 0; p < 8; p++)
                    xs += xm_part[((size_t)p * 64 + b) * U3 + j];
            }
            #pragma unroll
            for (int p = 0; p < 8; p++)
                hsum += hm_part[((size_t)p * 64 + b) * U3 + j];
            xv[g] = xs; hv[g] = hsum;
        }
        float z = 1.f / (1.f + expf(-(xv[0] + hv[0])));
        float r = 1.f / (1.f + expf(-(xv[1] + hv[1])));
        float hh = tanhf(xv[2] + r * hv[2]);
        float hn = z * h[(size_t)b * U + u] + (1.f - z) * hh;
        h[(size_t)b * U + u] = hn;
        hs[u] = hn;
        cat2[(size_t)b * 2 * U + u] = hn;
    }
    __syncthreads();

    const int wave = tid >> 6, lane = tid & 63;
    for (int s = wave; s < S; s += 4) {
        const float* kr = keys + ((size_t)b * S + s) * U;
        float acc = 0.f;
        #pragma unroll
        for (int c = 0; c < 4; c++) {
            int off = c * 256 + lane * 4;
            float4 kv = *(const float4*)(kr + off);
            float4 hv4 = *(const float4*)(hs + off);
            acc += kv.x * hv4.x + kv.y * hv4.y + kv.z * hv4.z + kv.w * hv4.w;
        }
        #pragma unroll
        for (int off = 32; off > 0; off >>= 1) acc += __shfl_down(acc, off);
        if (lane == 0) scores[b * S + s] = acc;
    }
}

// softmax + context (cat2 second half); grid (B, U/256)
__global__ __launch_bounds__(256) void ctxcat2_kernel(
    const float* __restrict__ scores, const float* __restrict__ memory,
    float* __restrict__ cat2)
{
    const int b = blockIdx.x;
    const int u = blockIdx.y * 256 + threadIdx.x;
    __shared__ float p[S];
    __shared__ float pn[S];
    if (threadIdx.x < S) p[threadIdx.x] = scores[b * S + threadIdx.x];
    __syncthreads();
    float m = -1e30f;
    #pragma unroll 8
    for (int s = 0; s < S; s++) m = fmaxf(m, p[s]);
    float sum = 0.f;
    #pragma unroll 8
    for (int s = 0; s < S; s++) sum += expf(p[s] - m);
    if (threadIdx.x < S) pn[threadIdx.x] = expf(p[threadIdx.x] - m) / sum;
    __syncthreads();
    float acc = 0.f;
    #pragma unroll 8
    for (int s = 0; s < S; s++)
        acc += pn[s] * memory[((size_t)b * S + s) * U + u];
    cat2[(size_t)b * 2 * U + U + u] = acc;
}

// attnv_all[t] = sum16(attn_part)
__global__ __launch_bounds__(256) void reduce_attnv(
    const float* __restrict__ attn_part, float* __restrict__ dst)
{
    int idx = blockIdx.x * 256 + threadIdx.x;   // B*U
    float s = 0.f;
    #pragma unroll
    for (int p = 0; p < 16; p++) s += attn_part[(size_t)p * B * U + idx];
    dst[idx] = s;
}

// ---------------------------------------------------------------------------
extern "C" void kernel_launch(void* const* d_in, const int* in_sizes, int n_in,
                              void* d_out, int out_size, void* d_ws, size_t ws_size,
                              hipStream_t stream)
{
    const int*   x      = (const int*)  d_in[0];
    const float* enc    = (const float*)d_in[1];
    const float* memory = (const float*)d_in[2];
    const float* emb    = (const float*)d_in[3];
    const float* gk     = (const float*)d_in[4];
    const float* grk    = (const float*)d_in[5];
    const float* gb     = (const float*)d_in[6];
    const float* memW   = (const float*)d_in[7];
    const float* attnW  = (const float*)d_in[8];
    const float* fcW    = (const float*)d_in[9];
    const float* fcb    = (const float*)d_in[10];
    float* out = (float*)d_out;

    char* p = (char*)d_ws;
    auto alloc = [&](size_t bytes) { char* r = p; p += (bytes + 255) & ~(size_t)255; return r; };
    ushortT* fcWp      = (ushortT*)alloc((size_t)U * V * 2);
    float*   keys      = (float*)  alloc((size_t)B * S * U * 4);
    float*   xe        = (float*)  alloc((size_t)T * B * U3 * 4);
    float*   xm_part   = (float*)  alloc((size_t)8 * B * U3 * 4);
    float*   hm_part   = (float*)  alloc((size_t)8 * B * U3 * 4);
    float*   attn_part = (float*)  alloc((size_t)16 * B * U * 4);
    float*   h         = (float*)  alloc((size_t)B * U * 4);
    float*   attnv_all = (float*)  alloc((size_t)T * B * U * 4);
    float*   cat2      = (float*)  alloc((size_t)B * 2 * U * 4);
    float*   scores    = (float*)  alloc((size_t)B * S * 4);
    ushortT* gkp       = (ushortT*)alloc((size_t)KXM * U3 * 2 * 3);
    ushortT* grkp      = (ushortT*)alloc((size_t)U * U3 * 2 * 3);
    ushortT* awp       = (ushortT*)alloc((size_t)2 * U * U * 2 * 3);
    ushortT* mwp       = (ushortT*)alloc((size_t)U * U * 2 * 3);
    const bool PS = (size_t)(p - (char*)d_ws) <= ws_size;

    dim3 blk(256);

    if (PS) {
        pack_w3<<<(size_t)KXM * U3 / 8 / 256, blk, 0, stream>>>(gk, gkp, U3, KXM);
        pack_w3<<<(size_t)U * U3 / 8 / 256, blk, 0, stream>>>(grk, grkp, U3, U);
        pack_w3<<<(size_t)2 * U * U / 8 / 256, blk, 0, stream>>>(attnW, awp, U, 2 * U);
        pack_w3<<<(size_t)U * U / 8 / 256, blk, 0, stream>>>(memW, mwp, U, U);
    }
    pack_w<<<(size_t)U * V / 8 / 256, blk, 0, stream>>>(fcW, fcWp, V, U);
    (void)hipMemcpyAsync(h, enc, (size_t)B * U * sizeof(float),
                         hipMemcpyDeviceToDevice, stream);

    if (PS) gemm_xe<true><<<dim3(U3 / 64, T), blk, 0, stream>>>(x, emb, gk, gkp, xe);
    else    gemm_xe<false><<<dim3(U3 / 64, T), blk, 0, stream>>>(x, emb, gk, gkp, xe);

    if (PS) gemm_keys<true><<<dim3(U / 128, B * S / 64), blk, 0, stream>>>(memory, memW, mwp, keys);
    else    gemm_keys<false><<<dim3(U / 128, B * S / 64), blk, 0, stream>>>(memory, memW, mwp, keys);

    GemmJob job_hm = { h,    grk,   grkp, (size_t)U * U3,    0, 32, hm_part,   U };
    GemmJob job_at = { cat2, attnW, awp,  (size_t)2 * U * U, 0, 64, attn_part, 2 * U };

    for (int t = 0; t < T; t++) {
        GemmJob job_xm = { attnv_all + (size_t)(t - 1) * B * U, gk, gkp,
                           (size_t)KXM * U3, 8, 40, xm_part, U };
        // ks=8, nkc=4: 768 blocks, half the serial k-chunk depth
        dim3 g1(U3 / 64, 8, t > 0 ? 2 : 1);
        if (PS) gemm6_ks2<true><<<g1, blk, 0, stream>>>(job_hm, job_xm, U3, 4);
        else    gemm6_ks2<false><<<g1, blk, 0, stream>>>(job_hm, job_xm, U3, 4);
        gs_fused<<<B, blk, 0, stream>>>(
            xe + (size_t)t * B * U3, xm_part, hm_part, gb, keys, h, cat2,
            scores, t > 0 ? 1 : 0);
        ctxcat2_kernel<<<dim3(B, U / 256), blk, 0, stream>>>(scores, memory, cat2);
        // ks=16, nkc=4: 256 blocks
        dim3 g2(U / 64, 16, 1);
        if (PS) gemm6_ks2<true><<<g2, blk, 0, stream>>>(job_at, job_at, U, 4);
        else    gemm6_ks2<false><<<g2, blk, 0, stream>>>(job_at, job_at, U, 4);
        reduce_attnv<<<B * U / 256, blk, 0, stream>>>(
            attn_part, attnv_all + (size_t)t * B * U);
    }

    // all logits at once: [T*64, U] @ [U, V] + fcb (M64, XCD-pinned)
    gemm_fcB<<<32 * T * 8, blk, 0, stream>>>(attnv_all, fcWp, fcb, out);
}